// Round 2
// baseline (8487.704 us; speedup 1.0000x reference)
//
#include <hip/hip_runtime.h>
#include <hip/hip_bf16.h>
#include <cstdint>
#include <cstddef>

#define T_STEPS 8192
#define D_OBS 256
#define D_ACT 16
#define D_MLP 1024
#define D_REC 1024
#define G3REC 3072

typedef short bf16x8_t __attribute__((ext_vector_type(8)));
typedef float f32x4_t __attribute__((ext_vector_type(4)));

__device__ __forceinline__ float b2f(unsigned short u) {
  union { uint32_t i; float f; } v; v.i = ((uint32_t)u) << 16; return v.f;
}
__device__ __forceinline__ unsigned short f2b(float f) {
  union { float f; uint32_t i; } v; v.f = f;
  uint32_t r = v.i + 0x7fffu + ((v.i >> 16) & 1u);
  return (unsigned short)(r >> 16);
}
__device__ __forceinline__ float mishf(float v) {
  float sp = (v > 15.f) ? v : log1pf(expf(v));
  return v * tanhf(sp);
}
__device__ __forceinline__ float sigmf(float x) { return 1.f / (1.f + expf(-x)); }

// ---- f32 -> bf16 conversion (inputs arrive as float32 on device) ----
__global__ __launch_bounds__(256) void cvt_f32_bf16(
    const float* __restrict__ in, unsigned short* __restrict__ out, int n4) {
  int stride = gridDim.x * blockDim.x;
  for (int j = blockIdx.x * blockDim.x + threadIdx.x; j < n4; j += stride) {
    float4 v = ((const float4*)in)[j];
    ushort4 o;
    o.x = f2b(v.x); o.y = f2b(v.y); o.z = f2b(v.z); o.w = f2b(v.w);
    ((ushort4*)out)[j] = o;
  }
}

// C[M,N] = act(A[M,K] @ B[N,K]^T + bias[N]); A,B,C bf16, bias f32, f32 accum.
// 128x128 tile, BK=32, 4 waves (2x2 of 64x64), mfma_f32_16x16x32_bf16.
template <int ACT>
__global__ __launch_bounds__(256) void gemm_tn_bf16(
    const unsigned short* __restrict__ A,
    const unsigned short* __restrict__ B,
    const float* __restrict__ bias,
    unsigned short* __restrict__ C,
    int M, int N, int K) {
  __shared__ unsigned short lds_a[128 * 32];
  __shared__ unsigned short lds_b[128 * 32];
  const int tid = threadIdx.x;
  const int lane = tid & 63;
  const int wave = tid >> 6;
  const int wr = wave >> 1, wc = wave & 1;
  const int row0 = blockIdx.x * 128, col0 = blockIdx.y * 128;
  f32x4_t acc[4][4] = {};
  const int lrow = lane & 15, kg = (lane >> 4) * 8;
  for (int k0 = 0; k0 < K; k0 += 32) {
#pragma unroll
    for (int p = 0; p < 2; ++p) {
      int i = tid + p * 256;          // 16B chunk id, 512 chunks per tile
      int r = i >> 2, c8 = (i & 3) * 8;
      *(int4*)&lds_a[i * 8] = *(const int4*)&A[(size_t)(row0 + r) * K + k0 + c8];
      *(int4*)&lds_b[i * 8] = *(const int4*)&B[(size_t)(col0 + r) * K + k0 + c8];
    }
    __syncthreads();
    bf16x8_t af[4], bfr[4];
#pragma unroll
    for (int m = 0; m < 4; ++m)
      af[m] = *(const bf16x8_t*)&lds_a[(wr * 64 + m * 16 + lrow) * 32 + kg];
#pragma unroll
    for (int n = 0; n < 4; ++n)
      bfr[n] = *(const bf16x8_t*)&lds_b[(wc * 64 + n * 16 + lrow) * 32 + kg];
#pragma unroll
    for (int m = 0; m < 4; ++m)
#pragma unroll
      for (int n = 0; n < 4; ++n)
        acc[m][n] = __builtin_amdgcn_mfma_f32_16x16x32_bf16(af[m], bfr[n], acc[m][n], 0, 0, 0);
    __syncthreads();
  }
  // C/D layout (verified m89/m91): col = lane&15, row = (lane>>4)*4 + j
#pragma unroll
  for (int n = 0; n < 4; ++n) {
    int col = col0 + wc * 64 + n * 16 + lrow;
    float bv = bias[col];
#pragma unroll
    for (int m = 0; m < 4; ++m) {
#pragma unroll
      for (int j = 0; j < 4; ++j) {
        int row = row0 + wr * 64 + m * 16 + (lane >> 4) * 4 + j;
        float v = acc[m][n][j] + bv;
        if (ACT) v = mishf(v);
        C[(size_t)row * N + col] = f2b(v);
      }
    }
  }
}

// start[] may arrive as int32 (documented "integer -> const int*") or as raw
// uint8 bools. Detect: int32 words of a 0/1 bool array are all <=1; packed
// uint8 words exceed 1 unless 192 consecutive bytes are zero (p ~ 2^-192).
__global__ void detect_start_mode(const unsigned int* __restrict__ w, int* __restrict__ mode) {
  if (threadIdx.x == 0 && blockIdx.x == 0) {
    int m = 0;
    for (int i = 0; i < 64; ++i)
      if (w[i] > 1u) m = 1;
    *mode = m;  // 1 = uint8, 0 = int32
  }
}
__device__ __forceinline__ int start_flag(const void* start, int mode, int t) {
  if (mode) return ((const unsigned char*)start)[t] != 0;
  return ((const int*)start)[t] != 0;
}

// One workgroup per segment start. start ~ Bernoulli(0.5) => ~4096 independent
// short chains (avg len 2). h kept f32 in LDS; w_hh matvec: 16 lanes per row.
__global__ __launch_bounds__(256) void gru_scan(
    const unsigned short* __restrict__ igates,  // [T,3072] bf16
    const void* __restrict__ start,
    const int* __restrict__ mode_p,
    const unsigned short* __restrict__ w_hh,    // [3072,1024] bf16 (converted)
    const float* __restrict__ b_n,              // [1024] f32
    const float* __restrict__ state0,           // [1024] f32
    unsigned short* __restrict__ states,        // [T,1024] bf16
    float* __restrict__ final_state) {          // [1024] f32 (d_out tail)
  const int mode = *mode_p;
  const int t0 = blockIdx.x;
  if (t0 > 0 && !start_flag(start, mode, t0)) return;
  __shared__ float h[D_REC];
  __shared__ float hg[G3REC];
  const int tid = threadIdx.x;
  const bool reset = start_flag(start, mode, t0) != 0;
  for (int u = tid; u < D_REC; u += 256)
    h[u] = reset ? 0.f : state0[u];
  __syncthreads();
  const int g = tid >> 4, l16 = tid & 15;
  for (int t = t0;; ++t) {
    // preload this lane's h slice into registers (64 f32, static indices)
    float hreg[64];
#pragma unroll
    for (int i = 0; i < 8; ++i) {
      float4 a = *(const float4*)&h[l16 * 8 + i * 128];
      float4 b = *(const float4*)&h[l16 * 8 + i * 128 + 4];
      hreg[i * 8 + 0] = a.x; hreg[i * 8 + 1] = a.y; hreg[i * 8 + 2] = a.z; hreg[i * 8 + 3] = a.w;
      hreg[i * 8 + 4] = b.x; hreg[i * 8 + 5] = b.y; hreg[i * 8 + 6] = b.z; hreg[i * 8 + 7] = b.w;
    }
    // hg = w_hh @ h : each 16-lane group does rows g, g+16, ... (192 rows)
    for (int row = g; row < G3REC; row += 16) {
      const unsigned short* wrow = w_hh + (size_t)row * D_REC;
      float s = 0.f;
#pragma unroll
      for (int i = 0; i < 8; ++i) {
        bf16x8_t wv = *(const bf16x8_t*)&wrow[l16 * 8 + i * 128];
#pragma unroll
        for (int j = 0; j < 8; ++j)
          s += b2f((unsigned short)wv[j]) * hreg[i * 8 + j];
      }
#pragma unroll
      for (int off = 1; off < 16; off <<= 1) s += __shfl_xor(s, off);
      if (l16 == 0) hg[row] = s;
    }
    __syncthreads();
    const size_t igbase = (size_t)t * G3REC;
    for (int u = tid; u < D_REC; u += 256) {
      float r = sigmf(b2f(igates[igbase + u]) + hg[u]);
      float z = sigmf(b2f(igates[igbase + D_REC + u]) + hg[D_REC + u]);
      float n = tanhf(b2f(igates[igbase + 2 * D_REC + u]) + r * (hg[2 * D_REC + u] + b_n[u]));
      float hn = n + z * (h[u] - n);  // equinox: h_new = n + z*(h-n)
      h[u] = hn;
      states[(size_t)t * D_REC + u] = f2b(hn);
      if (t == T_STEPS - 1) final_state[u] = hn;
    }
    if (t + 1 >= T_STEPS || start_flag(start, mode, t + 1)) break;
    __syncthreads();
  }
}

// One wave per row: 18 dot(1024) products + norm/advantage epilogue.
// y bf16 (internal), head weights/biases f32 (original inputs), q out f32.
__global__ __launch_bounds__(64) void heads_kernel(
    const unsigned short* __restrict__ y,  // [T,1024] bf16
    const float* __restrict__ Wv, const float* __restrict__ bv,
    const float* __restrict__ Wa, const float* __restrict__ ba,
    const float* __restrict__ Ws, const float* __restrict__ bs,
    float* __restrict__ q) {               // [T,16] f32
  const int t = blockIdx.x, lane = threadIdx.x;
  const unsigned short* yr = y + (size_t)t * D_MLP;
  float yv[16];
#pragma unroll
  for (int c = 0; c < 2; ++c) {
    bf16x8_t v = *(const bf16x8_t*)&yr[lane * 16 + c * 8];
#pragma unroll
    for (int j = 0; j < 8; ++j) yv[c * 8 + j] = b2f((unsigned short)v[j]);
  }
  float mine = 0.f;
  for (int o = 0; o < 18; ++o) {  // 0..15 = Wa rows, 16 = Wv, 17 = Ws
    const float* w = (o < 16) ? (Wa + (size_t)o * D_MLP) : (o == 16 ? Wv : Ws);
    float s = 0.f;
#pragma unroll
    for (int c = 0; c < 4; ++c) {
      float4 wv = *(const float4*)&w[lane * 16 + c * 4];
      s += wv.x * yv[c * 4 + 0] + wv.y * yv[c * 4 + 1] +
           wv.z * yv[c * 4 + 2] + wv.w * yv[c * 4 + 3];
    }
#pragma unroll
    for (int off = 1; off < 64; off <<= 1) s += __shfl_xor(s, off);
    if (lane == o) mine = s;
  }
  if (lane < 16) mine += ba[lane];
  else if (lane == 16) mine += bv[0];
  else if (lane == 17) mine += bs[0];
  float a = (lane < 16) ? mine : 0.f;
  float ss = a * a;
#pragma unroll
  for (int off = 1; off < 64; off <<= 1) ss += __shfl_xor(ss, off);
  float an = a / (1e-6f + sqrtf(ss));           // A / (1e-6 + ||A||)
  float ms = (lane < 16) ? an : 0.f;
#pragma unroll
  for (int off = 1; off < 64; off <<= 1) ms += __shfl_xor(ms, off);
  float adv = an - ms * (1.f / 16.f);           // A_normed - mean
  float val = __shfl(mine, 16);
  float sc = __shfl(mine, 17);
  if (lane < 16) q[(size_t)t * D_ACT + lane] = val + sc * adv;
}

extern "C" void kernel_launch(void* const* d_in, const int* in_sizes, int n_in,
                              void* d_out, int out_size, void* d_ws, size_t ws_size,
                              hipStream_t stream) {
  const float* x      = (const float*)d_in[0];
  const float* state0 = (const float*)d_in[1];
  const void*  start  = d_in[2];
  const float* W_pre  = (const float*)d_in[3];
  const float* b_pre  = (const float*)d_in[4];
  const float* w_ih   = (const float*)d_in[5];
  const float* w_hh   = (const float*)d_in[6];
  const float* b_ih   = (const float*)d_in[7];
  const float* b_n    = (const float*)d_in[8];
  const float* W1     = (const float*)d_in[9];
  const float* b1     = (const float*)d_in[10];
  const float* W2     = (const float*)d_in[11];
  const float* b2     = (const float*)d_in[12];
  const float* Wv     = (const float*)d_in[13];
  const float* bv     = (const float*)d_in[14];
  const float* Wa     = (const float*)d_in[15];
  const float* ba     = (const float*)d_in[16];
  const float* Ws     = (const float*)d_in[17];
  const float* bs     = (const float*)d_in[18];

  // workspace layout (bytes, MB = 1<<20):
  //   [  0M,  48M) igates bf16 [8192,3072]; tail 16MB reused as y2
  //   [ 48M,  64M) xp bf16 [8192,1024], reused as y1
  //   [ 64M,  80M) states bf16 [8192,1024]
  //   [ 80M,  84M) x_bf16 [8192,256]
  //   [ 84M,  85M) W_pre bf16
  //   [ 85M,  91M) w_ih bf16
  //   [ 91M,  97M) w_hh bf16
  //   [ 97M,  99M) W1 bf16
  //   [ 99M, 101M) W2 bf16
  //   [101M, ...]  mode flag
  char* ws = (char*)d_ws;
  const size_t MB = 1u << 20;
  unsigned short* igates = (unsigned short*)(ws);
  unsigned short* y2     = igates;
  unsigned short* xp     = (unsigned short*)(ws + 48 * MB);
  unsigned short* states = (unsigned short*)(ws + 64 * MB);
  unsigned short* x_bf   = (unsigned short*)(ws + 80 * MB);
  unsigned short* Wpre_bf= (unsigned short*)(ws + 84 * MB);
  unsigned short* wih_bf = (unsigned short*)(ws + 85 * MB);
  unsigned short* whh_bf = (unsigned short*)(ws + 91 * MB);
  unsigned short* W1_bf  = (unsigned short*)(ws + 97 * MB);
  unsigned short* W2_bf  = (unsigned short*)(ws + 99 * MB);
  int* mode_p            = (int*)(ws + 101 * MB);
  float* qout   = (float*)d_out;
  float* finals = qout + (size_t)T_STEPS * D_ACT;

  detect_start_mode<<<1, 64, 0, stream>>>((const unsigned int*)start, mode_p);
  cvt_f32_bf16<<<512, 256, 0, stream>>>(x,     x_bf,    (T_STEPS * D_OBS) / 4);
  cvt_f32_bf16<<<256, 256, 0, stream>>>(W_pre, Wpre_bf, (D_MLP * D_OBS) / 4);
  cvt_f32_bf16<<<768, 256, 0, stream>>>(w_ih,  wih_bf,  (G3REC * D_MLP) / 4);
  cvt_f32_bf16<<<768, 256, 0, stream>>>(w_hh,  whh_bf,  (G3REC * D_REC) / 4);
  cvt_f32_bf16<<<512, 256, 0, stream>>>(W1,    W1_bf,   (D_MLP * D_REC) / 4);
  cvt_f32_bf16<<<512, 256, 0, stream>>>(W2,    W2_bf,   (D_MLP * D_MLP) / 4);

  // xp = mish(x @ W_pre^T + b_pre)
  gemm_tn_bf16<1><<<dim3(64, 8), 256, 0, stream>>>(x_bf, Wpre_bf, b_pre, xp, T_STEPS, D_MLP, D_OBS);
  // igates = xp @ w_ih^T + b_ih
  gemm_tn_bf16<0><<<dim3(64, 24), 256, 0, stream>>>(xp, wih_bf, b_ih, igates, T_STEPS, G3REC, D_MLP);
  // segmented GRU scan
  gru_scan<<<T_STEPS, 256, 0, stream>>>(igates, start, mode_p, whh_bf, b_n, state0, states, finals);
  // y1 = mish(states @ W1^T + b1)   (into xp buffer)
  gemm_tn_bf16<1><<<dim3(64, 8), 256, 0, stream>>>(states, W1_bf, b1, xp, T_STEPS, D_MLP, D_REC);
  // y2 = mish(y1 @ W2^T + b2)       (into igates buffer tail region = y2)
  gemm_tn_bf16<1><<<dim3(64, 8), 256, 0, stream>>>(xp, W2_bf, b2, y2, T_STEPS, D_MLP, D_MLP);
  // heads + dueling epilogue
  heads_kernel<<<T_STEPS, 64, 0, stream>>>(y2, Wv, bv, Wa, ba, Ws, bs, qout);
}

// Round 3
// 837.132 us; speedup vs baseline: 10.1390x; 10.1390x over previous
//
#include <hip/hip_runtime.h>
#include <hip/hip_bf16.h>
#include <cstdint>
#include <cstddef>

#define T_STEPS 8192
#define D_OBS 256
#define D_ACT 16
#define D_MLP 1024
#define D_REC 1024
#define G3REC 3072
#define K_MAX 20          // wavefront iterations 0..K_MAX-1; cleanup handles len > K_MAX
#define HCAP 4608         // Hf32 row capacity (nseg ~ 4096 +/- 45; 11-sigma headroom)

typedef short bf16x8_t __attribute__((ext_vector_type(8)));
typedef float f32x4_t __attribute__((ext_vector_type(4)));

__device__ __forceinline__ float b2f(unsigned short u) {
  union { uint32_t i; float f; } v; v.i = ((uint32_t)u) << 16; return v.f;
}
__device__ __forceinline__ unsigned short f2b(float f) {
  union { float f; uint32_t i; } v; v.f = f;
  uint32_t r = v.i + 0x7fffu + ((v.i >> 16) & 1u);
  return (unsigned short)(r >> 16);
}
__device__ __forceinline__ float mishf(float v) {
  float sp = (v > 15.f) ? v : log1pf(expf(v));
  return v * tanhf(sp);
}
__device__ __forceinline__ float sigmf(float x) { return 1.f / (1.f + expf(-x)); }

// ---- f32 -> bf16 conversion ----
__global__ __launch_bounds__(256) void cvt_f32_bf16(
    const float* __restrict__ in, unsigned short* __restrict__ out, int n4) {
  int stride = gridDim.x * blockDim.x;
  for (int j = blockIdx.x * blockDim.x + threadIdx.x; j < n4; j += stride) {
    float4 v = ((const float4*)in)[j];
    ushort4 o;
    o.x = f2b(v.x); o.y = f2b(v.y); o.z = f2b(v.z); o.w = f2b(v.w);
    ((ushort4*)out)[j] = o;
  }
}

// w_hh [3072,1024] f32 -> w_perm bf16 with row permutation: out row 3u+g = in row g*1024+u.
__global__ __launch_bounds__(256) void cvt_whh_perm(
    const float* __restrict__ in, unsigned short* __restrict__ out) {
  int r = blockIdx.x;                 // original row
  int g = r >> 10, u = r & 1023;
  unsigned short* dst = out + (size_t)(u * 3 + g) * D_REC;
  const float* src = in + (size_t)r * D_REC;
  for (int c = threadIdx.x * 4; c < D_REC; c += 1024) {
    float4 v = *(const float4*)&src[c];
    ushort4 o; o.x = f2b(v.x); o.y = f2b(v.y); o.z = f2b(v.z); o.w = f2b(v.w);
    *(ushort4*)&dst[c] = o;
  }
}

// C[M,N] = act(A[M,K] @ B[N,K]^T + bias[N]); A,B,C bf16, bias f32, f32 accum.
template <int ACT>
__global__ __launch_bounds__(256) void gemm_tn_bf16(
    const unsigned short* __restrict__ A,
    const unsigned short* __restrict__ B,
    const float* __restrict__ bias,
    unsigned short* __restrict__ C,
    int M, int N, int K) {
  __shared__ unsigned short lds_a[128 * 32];
  __shared__ unsigned short lds_b[128 * 32];
  const int tid = threadIdx.x;
  const int lane = tid & 63;
  const int wave = tid >> 6;
  const int wr = wave >> 1, wc = wave & 1;
  const int row0 = blockIdx.x * 128, col0 = blockIdx.y * 128;
  f32x4_t acc[4][4] = {};
  const int lrow = lane & 15, kg = (lane >> 4) * 8;
  for (int k0 = 0; k0 < K; k0 += 32) {
#pragma unroll
    for (int p = 0; p < 2; ++p) {
      int i = tid + p * 256;
      int r = i >> 2, c8 = (i & 3) * 8;
      *(int4*)&lds_a[i * 8] = *(const int4*)&A[(size_t)(row0 + r) * K + k0 + c8];
      *(int4*)&lds_b[i * 8] = *(const int4*)&B[(size_t)(col0 + r) * K + k0 + c8];
    }
    __syncthreads();
    bf16x8_t af[4], bfr[4];
#pragma unroll
    for (int m = 0; m < 4; ++m)
      af[m] = *(const bf16x8_t*)&lds_a[(wr * 64 + m * 16 + lrow) * 32 + kg];
#pragma unroll
    for (int n = 0; n < 4; ++n)
      bfr[n] = *(const bf16x8_t*)&lds_b[(wc * 64 + n * 16 + lrow) * 32 + kg];
#pragma unroll
    for (int m = 0; m < 4; ++m)
#pragma unroll
      for (int n = 0; n < 4; ++n)
        acc[m][n] = __builtin_amdgcn_mfma_f32_16x16x32_bf16(af[m], bfr[n], acc[m][n], 0, 0, 0);
    __syncthreads();
  }
#pragma unroll
  for (int n = 0; n < 4; ++n) {
    int col = col0 + wc * 64 + n * 16 + lrow;
    float bv = bias[col];
#pragma unroll
    for (int m = 0; m < 4; ++m) {
#pragma unroll
      for (int j = 0; j < 4; ++j) {
        int row = row0 + wr * 64 + m * 16 + (lane >> 4) * 4 + j;
        float v = acc[m][n][j] + bv;
        if (ACT) v = mishf(v);
        C[(size_t)row * N + col] = f2b(v);
      }
    }
  }
}

// ---- start-flag dtype detection (int32 vs uint8) + nseg zeroing ----
__global__ void detect_start_mode(const unsigned int* __restrict__ w,
                                  int* __restrict__ mode, int* __restrict__ nseg) {
  if (threadIdx.x == 0 && blockIdx.x == 0) {
    int m = 0;
    for (int i = 0; i < 64; ++i)
      if (w[i] > 1u) m = 1;
    *mode = m;  // 1 = uint8, 0 = int32
    *nseg = 0;
  }
}
__device__ __forceinline__ int start_flag(const void* start, int mode, int t) {
  if (mode) return ((const unsigned char*)start)[t] != 0;
  return ((const int*)start)[t] != 0;
}

// ---- segment list: every t with (t==0 || start[t]) begins a segment ----
__global__ __launch_bounds__(256) void seg_build(
    const void* __restrict__ start, const int* __restrict__ mode_p,
    int* __restrict__ t0_raw, int* __restrict__ len_raw, int* __restrict__ nseg) {
  int t = blockIdx.x * blockDim.x + threadIdx.x;
  if (t >= T_STEPS) return;
  int mode = *mode_p;
  if (t != 0 && !start_flag(start, mode, t)) return;
  int len = 1;
  while (t + len < T_STEPS && !start_flag(start, mode, t + len)) ++len;
  int slot = atomicAdd(nseg, 1);
  t0_raw[slot] = t;
  len_raw[slot] = len;
}

// ---- counting sort by length (descending); counts[i] = #segments with len > i ----
__global__ __launch_bounds__(256) void seg_sort(
    const int* __restrict__ t0_raw, const int* __restrict__ len_raw,
    const int* __restrict__ nseg_p,
    int* __restrict__ t0s, int* __restrict__ len_s, int* __restrict__ counts) {
  __shared__ int hist[K_MAX + 2], off[K_MAX + 2];
  int tid = threadIdx.x;
  int n = *nseg_p;
  if (tid < K_MAX + 2) hist[tid] = 0;
  __syncthreads();
  for (int s = tid; s < n; s += 256)
    atomicAdd(&hist[min(len_raw[s], K_MAX + 1)], 1);
  __syncthreads();
  if (tid == 0) {
    int acc = 0;
    for (int b = K_MAX + 1; b >= 1; --b) { off[b] = acc; acc += hist[b]; }
    for (int i = 0; i <= K_MAX; ++i) {
      int c = 0;
      for (int b = i + 1; b <= K_MAX + 1; ++b) c += hist[b];
      counts[i] = c;
    }
  }
  __syncthreads();
  for (int s = tid; s < n; s += 256) {
    int pos = atomicAdd(&off[min(len_raw[s], K_MAX + 1)], 1);
    t0s[pos] = t0_raw[s];
    len_s[pos] = len_raw[s];
  }
}

// ---- hg0 = w_hh(f32) @ state0(f32): only segment containing t=0 needs a nonzero h ----
__global__ __launch_bounds__(256) void matvec0(
    const float* __restrict__ w_hh, const float* __restrict__ state0,
    float* __restrict__ hg0) {
  int g = threadIdx.x >> 4, l16 = threadIdx.x & 15;
  int row = blockIdx.x * 16 + g;
  const float* wr = w_hh + (size_t)row * D_REC;
  float s = 0.f;
#pragma unroll
  for (int i = 0; i < 16; ++i) {
    int c = (l16 + i * 16) * 4;
    float4 w4 = *(const float4*)&wr[c];
    float4 h4 = *(const float4*)&state0[c];
    s += w4.x * h4.x + w4.y * h4.y + w4.z * h4.z + w4.w * h4.w;
  }
#pragma unroll
  for (int o = 1; o < 16; o <<= 1) s += __shfl_xor(s, o);
  if (l16 == 0) hg0[row] = s;
}

// ---- iteration 0 gate: h_prev = state0 (seg at t=0, no reset) or 0 ----
__global__ __launch_bounds__(256) void gru_gate0(
    unsigned short* __restrict__ states, const unsigned short* __restrict__ igates,
    const void* __restrict__ start, const int* __restrict__ mode_p,
    const int* __restrict__ t0s, const int* __restrict__ nseg_p,
    const float* __restrict__ hg0, const float* __restrict__ state0,
    const float* __restrict__ b_n, float* __restrict__ Hf32,
    float* __restrict__ finals) {
  int p = blockIdx.x;
  if (p >= *nseg_p) return;
  int t0 = t0s[p];
  int mode = *mode_p;
  bool use_s0 = (t0 == 0) && !start_flag(start, mode, 0);
  size_t ib = (size_t)t0 * G3REC;
  for (int u = threadIdx.x; u < D_REC; u += 256) {
    float hp = use_s0 ? state0[u] : 0.f;
    float hr = use_s0 ? hg0[u] : 0.f;
    float hz = use_s0 ? hg0[D_REC + u] : 0.f;
    float hn = use_s0 ? hg0[2 * D_REC + u] : 0.f;
    float r = sigmf(b2f(igates[ib + u]) + hr);
    float z = sigmf(b2f(igates[ib + D_REC + u]) + hz);
    float n = tanhf(b2f(igates[ib + 2 * D_REC + u]) + r * (hn + b_n[u]));
    float hnew = n + z * (hp - n);
    if (p < HCAP) Hf32[(size_t)p * D_REC + u] = hnew;
    states[(size_t)t0 * D_REC + u] = f2b(hnew);
    if (t0 == T_STEPS - 1) finals[u] = hnew;
  }
}

// ---- fused wavefront iteration i>=1: hg GEMM (A gathered from states) + gate epilogue.
// Tile: 128 segments x 96 w_perm-rows (=32 units x 3 gates). 4 waves of 32x96.
__global__ __launch_bounds__(256) void gru_iter(
    unsigned short* __restrict__ states,
    const unsigned short* __restrict__ igates,
    const unsigned short* __restrict__ w_perm,
    const int* __restrict__ t0s, const int* __restrict__ counts,
    const float* __restrict__ b_n, float* __restrict__ Hf32,
    float* __restrict__ finals, int iter) {
  const int count = counts[iter];
  const int row0 = blockIdx.x * 128;
  if (row0 >= count) return;
  const int u0 = blockIdx.y * 32;
  const int col0 = u0 * 3;
  __shared__ __align__(16) float smem_f[128 * 98];        // 50176 B
  unsigned short* lds_a = (unsigned short*)smem_f;        // [128][32] bf16
  unsigned short* lds_b = (unsigned short*)smem_f + 4096; // [96][32] bf16
  float* hgl = smem_f;                                    // [128][98] f32 (after K-loop)
  const int tid = threadIdx.x;
  const int lane = tid & 63, wave = tid >> 6;
  const int rA = tid >> 2, c8 = (tid & 3) * 8;
  int gA0 = (row0 + rA < count) ? (t0s[row0 + rA] + iter - 1) : (t0s[0] + iter - 1);
  int gA1 = (row0 + rA + 64 < count) ? (t0s[row0 + rA + 64] + iter - 1) : (t0s[0] + iter - 1);
  const unsigned short* srcA0 = states + (size_t)gA0 * D_REC + c8;
  const unsigned short* srcA1 = states + (size_t)gA1 * D_REC + c8;
  const unsigned short* srcB0 = w_perm + (size_t)(col0 + rA) * D_REC + c8;
  const unsigned short* srcB1 = w_perm + (size_t)(col0 + 64 + rA) * D_REC + c8; // tid<128 only
  f32x4_t acc[2][6] = {};
  const int lrow = lane & 15, kg = (lane >> 4) * 8;
  for (int k0 = 0; k0 < D_REC; k0 += 32) {
    *(int4*)&lds_a[rA * 32 + c8] = *(const int4*)(srcA0 + k0);
    *(int4*)&lds_a[(rA + 64) * 32 + c8] = *(const int4*)(srcA1 + k0);
    *(int4*)&lds_b[rA * 32 + c8] = *(const int4*)(srcB0 + k0);
    if (tid < 128)
      *(int4*)&lds_b[(rA + 64) * 32 + c8] = *(const int4*)(srcB1 + k0);
    __syncthreads();
    bf16x8_t af[2], bfr[6];
#pragma unroll
    for (int m = 0; m < 2; ++m)
      af[m] = *(const bf16x8_t*)&lds_a[(wave * 32 + m * 16 + lrow) * 32 + kg];
#pragma unroll
    for (int n = 0; n < 6; ++n)
      bfr[n] = *(const bf16x8_t*)&lds_b[(n * 16 + lrow) * 32 + kg];
#pragma unroll
    for (int m = 0; m < 2; ++m)
#pragma unroll
      for (int n = 0; n < 6; ++n)
        acc[m][n] = __builtin_amdgcn_mfma_f32_16x16x32_bf16(af[m], bfr[n], acc[m][n], 0, 0, 0);
    __syncthreads();
  }
  // dump acc tile to LDS (row-local x 96 cols, stride 98 to dodge bank conflicts)
#pragma unroll
  for (int m = 0; m < 2; ++m)
#pragma unroll
    for (int n = 0; n < 6; ++n)
#pragma unroll
      for (int j = 0; j < 4; ++j) {
        int row = wave * 32 + m * 16 + (lane >> 4) * 4 + j;
        hgl[row * 98 + n * 16 + lrow] = acc[m][n][j];
      }
  __syncthreads();
  // gate epilogue: 128 segs x 32 units
  for (int idx = tid; idx < 128 * 32; idx += 256) {
    int pl = idx >> 5, ul = idx & 31;
    int p = row0 + pl;
    if (p >= count) continue;
    int t = t0s[p] + iter;
    int u = u0 + ul;
    float hr = hgl[pl * 98 + 3 * ul + 0];
    float hz = hgl[pl * 98 + 3 * ul + 1];
    float hn = hgl[pl * 98 + 3 * ul + 2];
    size_t ib = (size_t)t * G3REC;
    float hp = Hf32[(size_t)p * D_REC + u];
    float r = sigmf(b2f(igates[ib + u]) + hr);
    float z = sigmf(b2f(igates[ib + D_REC + u]) + hz);
    float n = tanhf(b2f(igates[ib + 2 * D_REC + u]) + r * (hn + b_n[u]));
    float hnew = n + z * (hp - n);
    Hf32[(size_t)p * D_REC + u] = hnew;
    states[(size_t)t * D_REC + u] = f2b(hnew);
    if (t == T_STEPS - 1) finals[u] = hnew;
  }
}

// ---- sequential tail for segments with len > K_MAX (w.h.p. none) ----
__global__ __launch_bounds__(256) void gru_cleanup(
    unsigned short* __restrict__ states, const unsigned short* __restrict__ igates,
    const unsigned short* __restrict__ w_perm,
    const int* __restrict__ t0s, const int* __restrict__ len_s,
    const int* __restrict__ counts, const float* __restrict__ b_n,
    const float* __restrict__ Hf32, float* __restrict__ finals) {
  int p = blockIdx.x;
  if (p >= counts[K_MAX]) return;  // segments with len > K_MAX (sorted first)
  int t0 = t0s[p], len = len_s[p];
  __shared__ float h[D_REC];
  __shared__ float hgl[G3REC];
  const int tid = threadIdx.x;
  for (int u = tid; u < D_REC; u += 256) h[u] = Hf32[(size_t)p * D_REC + u];
  __syncthreads();
  const int g = tid >> 4, l16 = tid & 15;
  for (int s = K_MAX; s < len; ++s) {
    int t = t0 + s;
    float hreg[64];
#pragma unroll
    for (int i = 0; i < 8; ++i) {
      float4 a = *(const float4*)&h[l16 * 8 + i * 128];
      float4 b = *(const float4*)&h[l16 * 8 + i * 128 + 4];
      hreg[i * 8 + 0] = a.x; hreg[i * 8 + 1] = a.y; hreg[i * 8 + 2] = a.z; hreg[i * 8 + 3] = a.w;
      hreg[i * 8 + 4] = b.x; hreg[i * 8 + 5] = b.y; hreg[i * 8 + 6] = b.z; hreg[i * 8 + 7] = b.w;
    }
    for (int row = g; row < G3REC; row += 16) {
      const unsigned short* wrow = w_perm + (size_t)row * D_REC;
      float sum = 0.f;
#pragma unroll
      for (int i = 0; i < 8; ++i) {
        bf16x8_t wv = *(const bf16x8_t*)&wrow[l16 * 8 + i * 128];
#pragma unroll
        for (int j = 0; j < 8; ++j)
          sum += b2f((unsigned short)wv[j]) * hreg[i * 8 + j];
      }
#pragma unroll
      for (int o = 1; o < 16; o <<= 1) sum += __shfl_xor(sum, o);
      if (l16 == 0) hgl[row] = sum;
    }
    __syncthreads();
    size_t ib = (size_t)t * G3REC;
    for (int u = tid; u < D_REC; u += 256) {
      float r = sigmf(b2f(igates[ib + u]) + hgl[3 * u + 0]);
      float z = sigmf(b2f(igates[ib + D_REC + u]) + hgl[3 * u + 1]);
      float n = tanhf(b2f(igates[ib + 2 * D_REC + u]) + r * (hgl[3 * u + 2] + b_n[u]));
      float hnew = n + z * (h[u] - n);
      h[u] = hnew;
      states[(size_t)t * D_REC + u] = f2b(hnew);
      if (t == T_STEPS - 1) finals[u] = hnew;
    }
    __syncthreads();
  }
}

// ---- heads + dueling epilogue (one wave per timestep) ----
__global__ __launch_bounds__(64) void heads_kernel(
    const unsigned short* __restrict__ y,
    const float* __restrict__ Wv, const float* __restrict__ bv,
    const float* __restrict__ Wa, const float* __restrict__ ba,
    const float* __restrict__ Ws, const float* __restrict__ bs,
    float* __restrict__ q) {
  const int t = blockIdx.x, lane = threadIdx.x;
  const unsigned short* yr = y + (size_t)t * D_MLP;
  float yv[16];
#pragma unroll
  for (int c = 0; c < 2; ++c) {
    bf16x8_t v = *(const bf16x8_t*)&yr[lane * 16 + c * 8];
#pragma unroll
    for (int j = 0; j < 8; ++j) yv[c * 8 + j] = b2f((unsigned short)v[j]);
  }
  float mine = 0.f;
  for (int o = 0; o < 18; ++o) {
    const float* w = (o < 16) ? (Wa + (size_t)o * D_MLP) : (o == 16 ? Wv : Ws);
    float s = 0.f;
#pragma unroll
    for (int c = 0; c < 4; ++c) {
      float4 wv = *(const float4*)&w[lane * 16 + c * 4];
      s += wv.x * yv[c * 4 + 0] + wv.y * yv[c * 4 + 1] +
           wv.z * yv[c * 4 + 2] + wv.w * yv[c * 4 + 3];
    }
#pragma unroll
    for (int off = 1; off < 64; off <<= 1) s += __shfl_xor(s, off);
    if (lane == o) mine = s;
  }
  if (lane < 16) mine += ba[lane];
  else if (lane == 16) mine += bv[0];
  else if (lane == 17) mine += bs[0];
  float a = (lane < 16) ? mine : 0.f;
  float ss = a * a;
#pragma unroll
  for (int off = 1; off < 64; off <<= 1) ss += __shfl_xor(ss, off);
  float an = a / (1e-6f + sqrtf(ss));
  float ms = (lane < 16) ? an : 0.f;
#pragma unroll
  for (int off = 1; off < 64; off <<= 1) ms += __shfl_xor(ms, off);
  float adv = an - ms * (1.f / 16.f);
  float val = __shfl(mine, 16);
  float sc = __shfl(mine, 17);
  if (lane < 16) q[(size_t)t * D_ACT + lane] = val + sc * adv;
}

extern "C" void kernel_launch(void* const* d_in, const int* in_sizes, int n_in,
                              void* d_out, int out_size, void* d_ws, size_t ws_size,
                              hipStream_t stream) {
  const float* x      = (const float*)d_in[0];
  const float* state0 = (const float*)d_in[1];
  const void*  start  = d_in[2];
  const float* W_pre  = (const float*)d_in[3];
  const float* b_pre  = (const float*)d_in[4];
  const float* w_ih   = (const float*)d_in[5];
  const float* w_hh   = (const float*)d_in[6];
  const float* b_ih   = (const float*)d_in[7];
  const float* b_n    = (const float*)d_in[8];
  const float* W1     = (const float*)d_in[9];
  const float* b1     = (const float*)d_in[10];
  const float* W2     = (const float*)d_in[11];
  const float* b2     = (const float*)d_in[12];
  const float* Wv     = (const float*)d_in[13];
  const float* bv     = (const float*)d_in[14];
  const float* Wa     = (const float*)d_in[15];
  const float* ba     = (const float*)d_in[16];
  const float* Ws     = (const float*)d_in[17];
  const float* bs     = (const float*)d_in[18];

  // workspace layout (phases: A=pre/igates, B=scan, C=post). Peak < 99 MB.
  //  [ 0,48M)  igates bf16 (A,B)          | y2 bf16 16MB (C)
  //  [48,64M)  xp bf16 (A)                | y1 bf16 (C)
  //  [48,66M)  Hf32 f32 [4608][1024] (B)  (overlaps xp/y1; disjoint in time)
  //  [66,82M)  states bf16 (B,C)
  //  [82,86M)  x_bf (A) | [82,88M) w_perm bf16 (B; converted after pre-GEMM)
  //  [88,88.5M) Wpre_bf | [88.5,94.5M) wih_bf (A)
  //  [94.5,96.5M) W1_bf | [96.5,98.5M) W2_bf (C)
  //  [98.5M+) seg arrays / counts / flags / hg0
  char* ws = (char*)d_ws;
  const size_t MB = 1ull << 20;
  unsigned short* igates = (unsigned short*)(ws);
  unsigned short* y2     = igates;
  unsigned short* xp     = (unsigned short*)(ws + 48 * MB);
  float*          Hf32   = (float*)(ws + 48 * MB);
  unsigned short* y1     = xp;
  unsigned short* states = (unsigned short*)(ws + 66 * MB);
  unsigned short* x_bf   = (unsigned short*)(ws + 82 * MB);
  unsigned short* w_perm = (unsigned short*)(ws + 82 * MB);
  unsigned short* Wpre_bf= (unsigned short*)(ws + 88 * MB);
  unsigned short* wih_bf = (unsigned short*)(ws + 88 * MB + 512 * 1024);
  unsigned short* W1_bf  = (unsigned short*)(ws + 94 * MB + 512 * 1024);
  unsigned short* W2_bf  = (unsigned short*)(ws + 96 * MB + 512 * 1024);
  char* seg = ws + 98 * MB + 512 * 1024;
  int* t0_raw  = (int*)(seg);
  int* len_raw = (int*)(seg + 32768);
  int* t0s     = (int*)(seg + 65536);
  int* len_s   = (int*)(seg + 98304);
  int* counts  = (int*)(seg + 131072);
  int* nseg_p  = (int*)(seg + 131072 + 128);
  int* mode_p  = (int*)(seg + 131072 + 192);
  float* hg0   = (float*)(seg + 131072 + 256);
  float* qout   = (float*)d_out;
  float* finals = qout + (size_t)T_STEPS * D_ACT;

  detect_start_mode<<<1, 64, 0, stream>>>((const unsigned int*)start, mode_p, nseg_p);
  cvt_f32_bf16<<<512, 256, 0, stream>>>(x,     x_bf,    (T_STEPS * D_OBS) / 4);
  cvt_f32_bf16<<<256, 256, 0, stream>>>(W_pre, Wpre_bf, (D_MLP * D_OBS) / 4);
  cvt_f32_bf16<<<768, 256, 0, stream>>>(w_ih,  wih_bf,  (G3REC * D_MLP) / 4);
  cvt_f32_bf16<<<512, 256, 0, stream>>>(W1,    W1_bf,   (D_MLP * D_REC) / 4);
  cvt_f32_bf16<<<512, 256, 0, stream>>>(W2,    W2_bf,   (D_MLP * D_MLP) / 4);
  seg_build<<<32, 256, 0, stream>>>(start, mode_p, t0_raw, len_raw, nseg_p);
  seg_sort<<<1, 256, 0, stream>>>(t0_raw, len_raw, nseg_p, t0s, len_s, counts);
  matvec0<<<192, 256, 0, stream>>>(w_hh, state0, hg0);

  // pre-MLP, then w_hh permute-convert (reuses x_bf region), then igates GEMM
  gemm_tn_bf16<1><<<dim3(64, 8), 256, 0, stream>>>(x_bf, Wpre_bf, b_pre, xp, T_STEPS, D_MLP, D_OBS);
  cvt_whh_perm<<<3072, 256, 0, stream>>>(w_hh, w_perm);
  gemm_tn_bf16<0><<<dim3(64, 24), 256, 0, stream>>>(xp, wih_bf, b_ih, igates, T_STEPS, G3REC, D_MLP);

  // wavefront scan
  gru_gate0<<<8192, 256, 0, stream>>>(states, igates, start, mode_p, t0s, nseg_p,
                                      hg0, state0, b_n, Hf32, finals);
  for (int i = 1; i < K_MAX; ++i) {
    int mt = (8192 / (i + 1) + 127) / 128;  // count_i <= 8192/(i+1)
    gru_iter<<<dim3(mt, 32), 256, 0, stream>>>(states, igates, w_perm, t0s, counts,
                                               b_n, Hf32, finals, i);
  }
  gru_cleanup<<<512, 256, 0, stream>>>(states, igates, w_perm, t0s, len_s, counts,
                                       b_n, Hf32, finals);

  // post MLP + heads
  gemm_tn_bf16<1><<<dim3(64, 8), 256, 0, stream>>>(states, W1_bf, b1, y1, T_STEPS, D_MLP, D_REC);
  gemm_tn_bf16<1><<<dim3(64, 8), 256, 0, stream>>>(y1, W2_bf, b2, y2, T_STEPS, D_MLP, D_MLP);
  heads_kernel<<<8192, 64, 0, stream>>>(y2, Wv, bv, Wa, ba, Ws, bs, qout);
}

// Round 4
// 766.523 us; speedup vs baseline: 11.0730x; 1.0921x over previous
//
#include <hip/hip_runtime.h>
#include <hip/hip_bf16.h>
#include <cstdint>
#include <cstddef>

#define T_STEPS 8192
#define D_OBS 256
#define D_ACT 16
#define D_MLP 1024
#define D_REC 1024
#define G3REC 3072
#define K_MAX 20          // wavefront iterations 0..K_MAX-1; cleanup handles len > K_MAX
#define HCAP 4608         // Hf32 row capacity (nseg ~ 4096 +/- 45; 11-sigma headroom)

typedef short bf16x8_t __attribute__((ext_vector_type(8)));
typedef float f32x4_t __attribute__((ext_vector_type(4)));

__device__ __forceinline__ float b2f(unsigned short u) {
  union { uint32_t i; float f; } v; v.i = ((uint32_t)u) << 16; return v.f;
}
__device__ __forceinline__ unsigned short f2b(float f) {
  union { float f; uint32_t i; } v; v.f = f;
  uint32_t r = v.i + 0x7fffu + ((v.i >> 16) & 1u);
  return (unsigned short)(r >> 16);
}
__device__ __forceinline__ float mishf(float v) {
  float sp = (v > 15.f) ? v : log1pf(expf(v));
  return v * tanhf(sp);
}
__device__ __forceinline__ float sigmf(float x) { return 1.f / (1.f + expf(-x)); }

// async global->LDS, 16B per lane; LDS dest = wave-uniform base + lane*16.
__device__ __forceinline__ void gload_lds16(const void* g, void* l) {
  __builtin_amdgcn_global_load_lds((const __attribute__((address_space(1))) void*)g,
                                   (__attribute__((address_space(3))) void*)l, 16, 0, 0);
}

// ---- f32 -> bf16 conversion ----
__global__ __launch_bounds__(256) void cvt_f32_bf16(
    const float* __restrict__ in, unsigned short* __restrict__ out, int n4) {
  int stride = gridDim.x * blockDim.x;
  for (int j = blockIdx.x * blockDim.x + threadIdx.x; j < n4; j += stride) {
    float4 v = ((const float4*)in)[j];
    ushort4 o;
    o.x = f2b(v.x); o.y = f2b(v.y); o.z = f2b(v.z); o.w = f2b(v.w);
    ((ushort4*)out)[j] = o;
  }
}

// w_hh [3072,1024] f32 -> w_perm bf16 with row permutation: out row 3u+g = in row g*1024+u.
__global__ __launch_bounds__(256) void cvt_whh_perm(
    const float* __restrict__ in, unsigned short* __restrict__ out) {
  int r = blockIdx.x;                 // original row
  int g = r >> 10, u = r & 1023;
  unsigned short* dst = out + (size_t)(u * 3 + g) * D_REC;
  const float* src = in + (size_t)r * D_REC;
  for (int c = threadIdx.x * 4; c < D_REC; c += 1024) {
    float4 v = *(const float4*)&src[c];
    ushort4 o; o.x = f2b(v.x); o.y = f2b(v.y); o.z = f2b(v.z); o.w = f2b(v.w);
    *(ushort4*)&dst[c] = o;
  }
}

// C[M,N] = act(A[M,K] @ B[N,K]^T + bias[N]); A,B,C bf16, bias f32, f32 accum.
// 128x128 tile, BK=32, 4 waves (2x2 of 64x64); global_load_lds staging (m97 structure).
template <int ACT>
__global__ __launch_bounds__(256) void gemm_tn_bf16(
    const unsigned short* __restrict__ A,
    const unsigned short* __restrict__ B,
    const float* __restrict__ bias,
    unsigned short* __restrict__ C,
    int M, int N, int K) {
  __shared__ unsigned short lds_a[128 * 32];
  __shared__ unsigned short lds_b[128 * 32];
  const int tid = threadIdx.x;
  const int lane = tid & 63;
  const int wave = tid >> 6;
  const int wr = wave >> 1, wc = wave & 1;
  const int row0 = blockIdx.x * 128, col0 = blockIdx.y * 128;
  f32x4_t acc[4][4] = {};
  const int lrow = lane & 15, kg = (lane >> 4) * 8;
  // staging: chunk i (i = p*256 + tid) covers LDS elements i*8..i*8+7,
  // global row = (p*64 + (tid>>2)), cols (tid&3)*8.. ; LDS base per (wave,p) is uniform.
  const int r = tid >> 2, c8 = (tid & 3) * 8;
  const unsigned short* gA0 = &A[(size_t)(row0 + r) * K + c8];
  const unsigned short* gA1 = &A[(size_t)(row0 + 64 + r) * K + c8];
  const unsigned short* gB0 = &B[(size_t)(col0 + r) * K + c8];
  const unsigned short* gB1 = &B[(size_t)(col0 + 64 + r) * K + c8];
  unsigned short* la = &lds_a[wave * 512];
  unsigned short* lb = &lds_b[wave * 512];
  for (int k0 = 0; k0 < K; k0 += 32) {
    gload_lds16(gA0 + k0, la);
    gload_lds16(gA1 + k0, la + 2048);
    gload_lds16(gB0 + k0, lb);
    gload_lds16(gB1 + k0, lb + 2048);
    __syncthreads();
    bf16x8_t af[4], bfr[4];
#pragma unroll
    for (int m = 0; m < 4; ++m)
      af[m] = *(const bf16x8_t*)&lds_a[(wr * 64 + m * 16 + lrow) * 32 + kg];
#pragma unroll
    for (int n = 0; n < 4; ++n)
      bfr[n] = *(const bf16x8_t*)&lds_b[(wc * 64 + n * 16 + lrow) * 32 + kg];
#pragma unroll
    for (int m = 0; m < 4; ++m)
#pragma unroll
      for (int n = 0; n < 4; ++n)
        acc[m][n] = __builtin_amdgcn_mfma_f32_16x16x32_bf16(af[m], bfr[n], acc[m][n], 0, 0, 0);
    __syncthreads();
  }
#pragma unroll
  for (int n = 0; n < 4; ++n) {
    int col = col0 + wc * 64 + n * 16 + lrow;
    float bv = bias[col];
#pragma unroll
    for (int m = 0; m < 4; ++m) {
#pragma unroll
      for (int j = 0; j < 4; ++j) {
        int row = row0 + wr * 64 + m * 16 + (lane >> 4) * 4 + j;
        float v = acc[m][n][j] + bv;
        if (ACT) v = mishf(v);
        C[(size_t)row * N + col] = f2b(v);
      }
    }
  }
}

// ---- start-flag dtype detection (int32 vs uint8) + nseg zeroing ----
__global__ void detect_start_mode(const unsigned int* __restrict__ w,
                                  int* __restrict__ mode, int* __restrict__ nseg) {
  if (threadIdx.x == 0 && blockIdx.x == 0) {
    int m = 0;
    for (int i = 0; i < 64; ++i)
      if (w[i] > 1u) m = 1;
    *mode = m;  // 1 = uint8, 0 = int32
    *nseg = 0;
  }
}
__device__ __forceinline__ int start_flag(const void* start, int mode, int t) {
  if (mode) return ((const unsigned char*)start)[t] != 0;
  return ((const int*)start)[t] != 0;
}

// ---- segment list: every t with (t==0 || start[t]) begins a segment ----
__global__ __launch_bounds__(256) void seg_build(
    const void* __restrict__ start, const int* __restrict__ mode_p,
    int* __restrict__ t0_raw, int* __restrict__ len_raw, int* __restrict__ nseg) {
  int t = blockIdx.x * blockDim.x + threadIdx.x;
  if (t >= T_STEPS) return;
  int mode = *mode_p;
  if (t != 0 && !start_flag(start, mode, t)) return;
  int len = 1;
  while (t + len < T_STEPS && !start_flag(start, mode, t + len)) ++len;
  int slot = atomicAdd(nseg, 1);
  t0_raw[slot] = t;
  len_raw[slot] = len;
}

// ---- counting sort by length (descending); counts[i] = #segments with len > i ----
__global__ __launch_bounds__(256) void seg_sort(
    const int* __restrict__ t0_raw, const int* __restrict__ len_raw,
    const int* __restrict__ nseg_p,
    int* __restrict__ t0s, int* __restrict__ len_s, int* __restrict__ counts) {
  __shared__ int hist[K_MAX + 2], off[K_MAX + 2];
  int tid = threadIdx.x;
  int n = *nseg_p;
  if (tid < K_MAX + 2) hist[tid] = 0;
  __syncthreads();
  for (int s = tid; s < n; s += 256)
    atomicAdd(&hist[min(len_raw[s], K_MAX + 1)], 1);
  __syncthreads();
  if (tid == 0) {
    int acc = 0;
    for (int b = K_MAX + 1; b >= 1; --b) { off[b] = acc; acc += hist[b]; }
    for (int i = 0; i <= K_MAX; ++i) {
      int c = 0;
      for (int b = i + 1; b <= K_MAX + 1; ++b) c += hist[b];
      counts[i] = c;
    }
  }
  __syncthreads();
  for (int s = tid; s < n; s += 256) {
    int pos = atomicAdd(&off[min(len_raw[s], K_MAX + 1)], 1);
    t0s[pos] = t0_raw[s];
    len_s[pos] = len_raw[s];
  }
}

// ---- hg0 = w_hh(f32) @ state0(f32): only segment containing t=0 needs a nonzero h ----
__global__ __launch_bounds__(256) void matvec0(
    const float* __restrict__ w_hh, const float* __restrict__ state0,
    float* __restrict__ hg0) {
  int g = threadIdx.x >> 4, l16 = threadIdx.x & 15;
  int row = blockIdx.x * 16 + g;
  const float* wr = w_hh + (size_t)row * D_REC;
  float s = 0.f;
#pragma unroll
  for (int i = 0; i < 16; ++i) {
    int c = (l16 + i * 16) * 4;
    float4 w4 = *(const float4*)&wr[c];
    float4 h4 = *(const float4*)&state0[c];
    s += w4.x * h4.x + w4.y * h4.y + w4.z * h4.z + w4.w * h4.w;
  }
#pragma unroll
  for (int o = 1; o < 16; o <<= 1) s += __shfl_xor(s, o);
  if (l16 == 0) hg0[row] = s;
}

// ---- iteration 0 gate: h_prev = state0 (seg at t=0, no reset) or 0 ----
__global__ __launch_bounds__(256) void gru_gate0(
    unsigned short* __restrict__ states, const unsigned short* __restrict__ igates,
    const void* __restrict__ start, const int* __restrict__ mode_p,
    const int* __restrict__ t0s, const int* __restrict__ nseg_p,
    const float* __restrict__ hg0, const float* __restrict__ state0,
    const float* __restrict__ b_n, float* __restrict__ Hf32,
    float* __restrict__ finals) {
  int p = blockIdx.x;
  if (p >= *nseg_p) return;
  int t0 = t0s[p];
  int mode = *mode_p;
  bool use_s0 = (t0 == 0) && !start_flag(start, mode, 0);
  size_t ib = (size_t)t0 * G3REC;
  for (int u = threadIdx.x; u < D_REC; u += 256) {
    float hp = use_s0 ? state0[u] : 0.f;
    float hr = use_s0 ? hg0[u] : 0.f;
    float hz = use_s0 ? hg0[D_REC + u] : 0.f;
    float hn = use_s0 ? hg0[2 * D_REC + u] : 0.f;
    float r = sigmf(b2f(igates[ib + u]) + hr);
    float z = sigmf(b2f(igates[ib + D_REC + u]) + hz);
    float n = tanhf(b2f(igates[ib + 2 * D_REC + u]) + r * (hn + b_n[u]));
    float hnew = n + z * (hp - n);
    if (p < HCAP) Hf32[(size_t)p * D_REC + u] = hnew;
    states[(size_t)t0 * D_REC + u] = f2b(hnew);
    if (t0 == T_STEPS - 1) finals[u] = hnew;
  }
}

// ---- fused wavefront iteration i>=1: hg GEMM (A gathered from states) + gate epilogue.
// Tile: 128 segments x 96 w_perm-rows (=32 units x 3 gates). 4 waves of 32x96.
__global__ __launch_bounds__(256) void gru_iter(
    unsigned short* __restrict__ states,
    const unsigned short* __restrict__ igates,
    const unsigned short* __restrict__ w_perm,
    const int* __restrict__ t0s, const int* __restrict__ counts,
    const float* __restrict__ b_n, float* __restrict__ Hf32,
    float* __restrict__ finals, int iter) {
  const int count = counts[iter];
  const int row0 = blockIdx.x * 128;
  if (row0 >= count) return;
  const int u0 = blockIdx.y * 32;
  const int col0 = u0 * 3;
  __shared__ __align__(16) float smem_f[128 * 98];        // 50176 B
  unsigned short* lds_a = (unsigned short*)smem_f;        // [128][32] bf16
  unsigned short* lds_b = (unsigned short*)smem_f + 4096; // [96][32] bf16
  float* hgl = smem_f;                                    // [128][98] f32 (after K-loop)
  const int tid = threadIdx.x;
  const int lane = tid & 63, wave = tid >> 6;
  const int rA = tid >> 2, c8 = (tid & 3) * 8;
  int gA0 = (row0 + rA < count) ? (t0s[row0 + rA] + iter - 1) : (t0s[0] + iter - 1);
  int gA1 = (row0 + rA + 64 < count) ? (t0s[row0 + rA + 64] + iter - 1) : (t0s[0] + iter - 1);
  const unsigned short* srcA0 = states + (size_t)gA0 * D_REC + c8;
  const unsigned short* srcA1 = states + (size_t)gA1 * D_REC + c8;
  const unsigned short* srcB0 = w_perm + (size_t)(col0 + rA) * D_REC + c8;
  const unsigned short* srcB1 = w_perm + (size_t)(col0 + 64 + rA) * D_REC + c8; // waves 0,1
  unsigned short* la = lds_a + wave * 512;
  unsigned short* lb = lds_b + wave * 512;
  f32x4_t acc[2][6] = {};
  const int lrow = lane & 15, kg = (lane >> 4) * 8;
  for (int k0 = 0; k0 < D_REC; k0 += 32) {
    gload_lds16(srcA0 + k0, la);
    gload_lds16(srcA1 + k0, la + 2048);
    gload_lds16(srcB0 + k0, lb);
    if (wave < 2)
      gload_lds16(srcB1 + k0, lb + 2048);
    __syncthreads();
    bf16x8_t af[2], bfr[6];
#pragma unroll
    for (int m = 0; m < 2; ++m)
      af[m] = *(const bf16x8_t*)&lds_a[(wave * 32 + m * 16 + lrow) * 32 + kg];
#pragma unroll
    for (int n = 0; n < 6; ++n)
      bfr[n] = *(const bf16x8_t*)&lds_b[(n * 16 + lrow) * 32 + kg];
#pragma unroll
    for (int m = 0; m < 2; ++m)
#pragma unroll
      for (int n = 0; n < 6; ++n)
        acc[m][n] = __builtin_amdgcn_mfma_f32_16x16x32_bf16(af[m], bfr[n], acc[m][n], 0, 0, 0);
    __syncthreads();
  }
  // dump acc tile to LDS (row-local x 96 cols, stride 98 to dodge bank conflicts)
#pragma unroll
  for (int m = 0; m < 2; ++m)
#pragma unroll
    for (int n = 0; n < 6; ++n)
#pragma unroll
      for (int j = 0; j < 4; ++j) {
        int row = wave * 32 + m * 16 + (lane >> 4) * 4 + j;
        hgl[row * 98 + n * 16 + lrow] = acc[m][n][j];
      }
  __syncthreads();
  // gate epilogue: 128 segs x 32 units
  for (int idx = tid; idx < 128 * 32; idx += 256) {
    int pl = idx >> 5, ul = idx & 31;
    int p = row0 + pl;
    if (p >= count) continue;
    int t = t0s[p] + iter;
    int u = u0 + ul;
    float hr = hgl[pl * 98 + 3 * ul + 0];
    float hz = hgl[pl * 98 + 3 * ul + 1];
    float hn = hgl[pl * 98 + 3 * ul + 2];
    size_t ib = (size_t)t * G3REC;
    float hp = Hf32[(size_t)p * D_REC + u];
    float r = sigmf(b2f(igates[ib + u]) + hr);
    float z = sigmf(b2f(igates[ib + D_REC + u]) + hz);
    float n = tanhf(b2f(igates[ib + 2 * D_REC + u]) + r * (hn + b_n[u]));
    float hnew = n + z * (hp - n);
    Hf32[(size_t)p * D_REC + u] = hnew;
    states[(size_t)t * D_REC + u] = f2b(hnew);
    if (t == T_STEPS - 1) finals[u] = hnew;
  }
}

// ---- sequential tail for segments with len > K_MAX (w.h.p. none) ----
__global__ __launch_bounds__(256) void gru_cleanup(
    unsigned short* __restrict__ states, const unsigned short* __restrict__ igates,
    const unsigned short* __restrict__ w_perm,
    const int* __restrict__ t0s, const int* __restrict__ len_s,
    const int* __restrict__ counts, const float* __restrict__ b_n,
    const float* __restrict__ Hf32, float* __restrict__ finals) {
  int p = blockIdx.x;
  if (p >= counts[K_MAX]) return;  // segments with len > K_MAX (sorted first)
  int t0 = t0s[p], len = len_s[p];
  __shared__ float h[D_REC];
  __shared__ float hgl[G3REC];
  const int tid = threadIdx.x;
  for (int u = tid; u < D_REC; u += 256) h[u] = Hf32[(size_t)p * D_REC + u];
  __syncthreads();
  const int g = tid >> 4, l16 = tid & 15;
  for (int s = K_MAX; s < len; ++s) {
    int t = t0 + s;
    float hreg[64];
#pragma unroll
    for (int i = 0; i < 8; ++i) {
      float4 a = *(const float4*)&h[l16 * 8 + i * 128];
      float4 b = *(const float4*)&h[l16 * 8 + i * 128 + 4];
      hreg[i * 8 + 0] = a.x; hreg[i * 8 + 1] = a.y; hreg[i * 8 + 2] = a.z; hreg[i * 8 + 3] = a.w;
      hreg[i * 8 + 4] = b.x; hreg[i * 8 + 5] = b.y; hreg[i * 8 + 6] = b.z; hreg[i * 8 + 7] = b.w;
    }
    for (int row = g; row < G3REC; row += 16) {
      const unsigned short* wrow = w_perm + (size_t)row * D_REC;
      float sum = 0.f;
#pragma unroll
      for (int i = 0; i < 8; ++i) {
        bf16x8_t wv = *(const bf16x8_t*)&wrow[l16 * 8 + i * 128];
#pragma unroll
        for (int j = 0; j < 8; ++j)
          sum += b2f((unsigned short)wv[j]) * hreg[i * 8 + j];
      }
#pragma unroll
      for (int o = 1; o < 16; o <<= 1) sum += __shfl_xor(sum, o);
      if (l16 == 0) hgl[row] = sum;
    }
    __syncthreads();
    size_t ib = (size_t)t * G3REC;
    for (int u = tid; u < D_REC; u += 256) {
      float r = sigmf(b2f(igates[ib + u]) + hgl[3 * u + 0]);
      float z = sigmf(b2f(igates[ib + D_REC + u]) + hgl[3 * u + 1]);
      float n = tanhf(b2f(igates[ib + 2 * D_REC + u]) + r * (hgl[3 * u + 2] + b_n[u]));
      float hnew = n + z * (h[u] - n);
      h[u] = hnew;
      states[(size_t)t * D_REC + u] = f2b(hnew);
      if (t == T_STEPS - 1) finals[u] = hnew;
    }
    __syncthreads();
  }
}

// ---- heads + dueling epilogue (one wave per timestep) ----
__global__ __launch_bounds__(64) void heads_kernel(
    const unsigned short* __restrict__ y,
    const float* __restrict__ Wv, const float* __restrict__ bv,
    const float* __restrict__ Wa, const float* __restrict__ ba,
    const float* __restrict__ Ws, const float* __restrict__ bs,
    float* __restrict__ q) {
  const int t = blockIdx.x, lane = threadIdx.x;
  const unsigned short* yr = y + (size_t)t * D_MLP;
  float yv[16];
#pragma unroll
  for (int c = 0; c < 2; ++c) {
    bf16x8_t v = *(const bf16x8_t*)&yr[lane * 16 + c * 8];
#pragma unroll
    for (int j = 0; j < 8; ++j) yv[c * 8 + j] = b2f((unsigned short)v[j]);
  }
  float mine = 0.f;
  for (int o = 0; o < 18; ++o) {
    const float* w = (o < 16) ? (Wa + (size_t)o * D_MLP) : (o == 16 ? Wv : Ws);
    float s = 0.f;
#pragma unroll
    for (int c = 0; c < 4; ++c) {
      float4 wv = *(const float4*)&w[lane * 16 + c * 4];
      s += wv.x * yv[c * 4 + 0] + wv.y * yv[c * 4 + 1] +
           wv.z * yv[c * 4 + 2] + wv.w * yv[c * 4 + 3];
    }
#pragma unroll
    for (int off = 1; off < 64; off <<= 1) s += __shfl_xor(s, off);
    if (lane == o) mine = s;
  }
  if (lane < 16) mine += ba[lane];
  else if (lane == 16) mine += bv[0];
  else if (lane == 17) mine += bs[0];
  float a = (lane < 16) ? mine : 0.f;
  float ss = a * a;
#pragma unroll
  for (int off = 1; off < 64; off <<= 1) ss += __shfl_xor(ss, off);
  float an = a / (1e-6f + sqrtf(ss));
  float ms = (lane < 16) ? an : 0.f;
#pragma unroll
  for (int off = 1; off < 64; off <<= 1) ms += __shfl_xor(ms, off);
  float adv = an - ms * (1.f / 16.f);
  float val = __shfl(mine, 16);
  float sc = __shfl(mine, 17);
  if (lane < 16) q[(size_t)t * D_ACT + lane] = val + sc * adv;
}

extern "C" void kernel_launch(void* const* d_in, const int* in_sizes, int n_in,
                              void* d_out, int out_size, void* d_ws, size_t ws_size,
                              hipStream_t stream) {
  const float* x      = (const float*)d_in[0];
  const float* state0 = (const float*)d_in[1];
  const void*  start  = d_in[2];
  const float* W_pre  = (const float*)d_in[3];
  const float* b_pre  = (const float*)d_in[4];
  const float* w_ih   = (const float*)d_in[5];
  const float* w_hh   = (const float*)d_in[6];
  const float* b_ih   = (const float*)d_in[7];
  const float* b_n    = (const float*)d_in[8];
  const float* W1     = (const float*)d_in[9];
  const float* b1     = (const float*)d_in[10];
  const float* W2     = (const float*)d_in[11];
  const float* b2     = (const float*)d_in[12];
  const float* Wv     = (const float*)d_in[13];
  const float* bv     = (const float*)d_in[14];
  const float* Wa     = (const float*)d_in[15];
  const float* ba     = (const float*)d_in[16];
  const float* Ws     = (const float*)d_in[17];
  const float* bs     = (const float*)d_in[18];

  // workspace layout (phases: A=pre/igates, B=scan, C=post). Peak < 99 MB.
  char* ws = (char*)d_ws;
  const size_t MB = 1ull << 20;
  unsigned short* igates = (unsigned short*)(ws);
  unsigned short* y2     = igates;
  unsigned short* xp     = (unsigned short*)(ws + 48 * MB);
  float*          Hf32   = (float*)(ws + 48 * MB);
  unsigned short* y1     = xp;
  unsigned short* states = (unsigned short*)(ws + 66 * MB);
  unsigned short* x_bf   = (unsigned short*)(ws + 82 * MB);
  unsigned short* w_perm = (unsigned short*)(ws + 82 * MB);
  unsigned short* Wpre_bf= (unsigned short*)(ws + 88 * MB);
  unsigned short* wih_bf = (unsigned short*)(ws + 88 * MB + 512 * 1024);
  unsigned short* W1_bf  = (unsigned short*)(ws + 94 * MB + 512 * 1024);
  unsigned short* W2_bf  = (unsigned short*)(ws + 96 * MB + 512 * 1024);
  char* seg = ws + 98 * MB + 512 * 1024;
  int* t0_raw  = (int*)(seg);
  int* len_raw = (int*)(seg + 32768);
  int* t0s     = (int*)(seg + 65536);
  int* len_s   = (int*)(seg + 98304);
  int* counts  = (int*)(seg + 131072);
  int* nseg_p  = (int*)(seg + 131072 + 128);
  int* mode_p  = (int*)(seg + 131072 + 192);
  float* hg0   = (float*)(seg + 131072 + 256);
  float* qout   = (float*)d_out;
  float* finals = qout + (size_t)T_STEPS * D_ACT;

  detect_start_mode<<<1, 64, 0, stream>>>((const unsigned int*)start, mode_p, nseg_p);
  cvt_f32_bf16<<<512, 256, 0, stream>>>(x,     x_bf,    (T_STEPS * D_OBS) / 4);
  cvt_f32_bf16<<<256, 256, 0, stream>>>(W_pre, Wpre_bf, (D_MLP * D_OBS) / 4);
  cvt_f32_bf16<<<768, 256, 0, stream>>>(w_ih,  wih_bf,  (G3REC * D_MLP) / 4);
  cvt_f32_bf16<<<512, 256, 0, stream>>>(W1,    W1_bf,   (D_MLP * D_REC) / 4);
  cvt_f32_bf16<<<512, 256, 0, stream>>>(W2,    W2_bf,   (D_MLP * D_MLP) / 4);
  seg_build<<<32, 256, 0, stream>>>(start, mode_p, t0_raw, len_raw, nseg_p);
  seg_sort<<<1, 256, 0, stream>>>(t0_raw, len_raw, nseg_p, t0s, len_s, counts);
  matvec0<<<192, 256, 0, stream>>>(w_hh, state0, hg0);

  // pre-MLP, then w_hh permute-convert (reuses x_bf region), then igates GEMM
  gemm_tn_bf16<1><<<dim3(64, 8), 256, 0, stream>>>(x_bf, Wpre_bf, b_pre, xp, T_STEPS, D_MLP, D_OBS);
  cvt_whh_perm<<<3072, 256, 0, stream>>>(w_hh, w_perm);
  gemm_tn_bf16<0><<<dim3(64, 24), 256, 0, stream>>>(xp, wih_bf, b_ih, igates, T_STEPS, G3REC, D_MLP);

  // wavefront scan
  gru_gate0<<<8192, 256, 0, stream>>>(states, igates, start, mode_p, t0s, nseg_p,
                                      hg0, state0, b_n, Hf32, finals);
  for (int i = 1; i < K_MAX; ++i) {
    int mt = (8192 / (i + 1) + 127) / 128;  // count_i <= 8192/(i+1)
    gru_iter<<<dim3(mt, 32), 256, 0, stream>>>(states, igates, w_perm, t0s, counts,
                                               b_n, Hf32, finals, i);
  }
  gru_cleanup<<<512, 256, 0, stream>>>(states, igates, w_perm, t0s, len_s, counts,
                                       b_n, Hf32, finals);

  // post MLP + heads
  gemm_tn_bf16<1><<<dim3(64, 8), 256, 0, stream>>>(states, W1_bf, b1, y1, T_STEPS, D_MLP, D_REC);
  gemm_tn_bf16<1><<<dim3(64, 8), 256, 0, stream>>>(y1, W2_bf, b2, y2, T_STEPS, D_MLP, D_MLP);
  heads_kernel<<<8192, 64, 0, stream>>>(y2, Wv, bv, Wa, ba, Ws, bs, qout);
}

// Round 5
// 736.737 us; speedup vs baseline: 11.5207x; 1.0404x over previous
//
#include <hip/hip_runtime.h>
#include <hip/hip_bf16.h>
#include <cstdint>
#include <cstddef>

#define T_STEPS 8192
#define D_OBS 256
#define D_ACT 16
#define D_MLP 1024
#define D_REC 1024
#define G3REC 3072
#define K_MAX 20          // wavefront iterations 0..K_MAX-1; cleanup handles len > K_MAX
#define HCAP 4608         // Hf32 row capacity (nseg ~ 4096 +/- 45; 11-sigma headroom)

typedef short bf16x8_t __attribute__((ext_vector_type(8)));
typedef float f32x4_t __attribute__((ext_vector_type(4)));

__device__ __forceinline__ float b2f(unsigned short u) {
  union { uint32_t i; float f; } v; v.i = ((uint32_t)u) << 16; return v.f;
}
__device__ __forceinline__ unsigned short f2b(float f) {
  union { float f; uint32_t i; } v; v.f = f;
  uint32_t r = v.i + 0x7fffu + ((v.i >> 16) & 1u);
  return (unsigned short)(r >> 16);
}
__device__ __forceinline__ float mishf(float v) {
  float sp = (v > 15.f) ? v : log1pf(expf(v));
  return v * tanhf(sp);
}
__device__ __forceinline__ float sigmf(float x) { return 1.f / (1.f + expf(-x)); }

// async global->LDS, 16B per lane; LDS dest = wave-uniform base + lane*16.
__device__ __forceinline__ void gload_lds16(const void* g, void* l) {
  __builtin_amdgcn_global_load_lds((const __attribute__((address_space(1))) void*)g,
                                   (__attribute__((address_space(3))) void*)l, 16, 0, 0);
}

// ---- f32 -> bf16 conversion ----
__global__ __launch_bounds__(256) void cvt_f32_bf16(
    const float* __restrict__ in, unsigned short* __restrict__ out, int n4) {
  int stride = gridDim.x * blockDim.x;
  for (int j = blockIdx.x * blockDim.x + threadIdx.x; j < n4; j += stride) {
    float4 v = ((const float4*)in)[j];
    ushort4 o;
    o.x = f2b(v.x); o.y = f2b(v.y); o.z = f2b(v.z); o.w = f2b(v.w);
    ((ushort4*)out)[j] = o;
  }
}

// w_hh [3072,1024] f32 -> w_perm bf16 with row permutation: out row 3u+g = in row g*1024+u.
__global__ __launch_bounds__(256) void cvt_whh_perm(
    const float* __restrict__ in, unsigned short* __restrict__ out) {
  int r = blockIdx.x;                 // original row
  int g = r >> 10, u = r & 1023;
  unsigned short* dst = out + (size_t)(u * 3 + g) * D_REC;
  const float* src = in + (size_t)r * D_REC;
  for (int c = threadIdx.x * 4; c < D_REC; c += 1024) {
    float4 v = *(const float4*)&src[c];
    ushort4 o; o.x = f2b(v.x); o.y = f2b(v.y); o.z = f2b(v.z); o.w = f2b(v.w);
    *(ushort4*)&dst[c] = o;
  }
}

// C[M,N] = act(A[M,K] @ B[N,K]^T + bias[N]); A,B,C bf16, bias f32, f32 accum.
// 128x128 tile, BK=32, 4 waves; DOUBLE-BUFFERED global_load_lds pipeline (T3 2-phase):
//   stage(next) -> ds_read(cur)+MFMA -> barrier(vmcnt0+lgkm0) -> swap.
template <int ACT>
__global__ __launch_bounds__(256) void gemm_tn_bf16(
    const unsigned short* __restrict__ A,
    const unsigned short* __restrict__ B,
    const float* __restrict__ bias,
    unsigned short* __restrict__ C,
    int M, int N, int K) {
  __shared__ unsigned short lds_a[2 * 128 * 32];
  __shared__ unsigned short lds_b[2 * 128 * 32];
  const int tid = threadIdx.x;
  const int lane = tid & 63;
  const int wave = tid >> 6;
  const int wr = wave >> 1, wc = wave & 1;
  const int row0 = blockIdx.x * 128, col0 = blockIdx.y * 128;
  f32x4_t acc[4][4] = {};
  const int lrow = lane & 15, kg = (lane >> 4) * 8;
  const int r = tid >> 2, c8 = (tid & 3) * 8;
  const unsigned short* gA0 = &A[(size_t)(row0 + r) * K + c8];
  const unsigned short* gA1 = &A[(size_t)(row0 + 64 + r) * K + c8];
  const unsigned short* gB0 = &B[(size_t)(col0 + r) * K + c8];
  const unsigned short* gB1 = &B[(size_t)(col0 + 64 + r) * K + c8];
  const int so = wave * 512;  // per-wave LDS staging base (elements)
  auto stage = [&](int buf, int k0) {
    unsigned short* la = &lds_a[buf * 4096 + so];
    unsigned short* lb = &lds_b[buf * 4096 + so];
    gload_lds16(gA0 + k0, la);
    gload_lds16(gA1 + k0, la + 2048);
    gload_lds16(gB0 + k0, lb);
    gload_lds16(gB1 + k0, lb + 2048);
  };
  const int nk = K >> 5;
  stage(0, 0);
  __syncthreads();
  int cur = 0;
  for (int t = 0; t < nk; ++t) {
    if (t + 1 < nk) stage(cur ^ 1, (t + 1) << 5);
    const unsigned short* ca = &lds_a[cur * 4096];
    const unsigned short* cb = &lds_b[cur * 4096];
    bf16x8_t af[4], bfr[4];
#pragma unroll
    for (int m = 0; m < 4; ++m)
      af[m] = *(const bf16x8_t*)&ca[(wr * 64 + m * 16 + lrow) * 32 + kg];
#pragma unroll
    for (int n = 0; n < 4; ++n)
      bfr[n] = *(const bf16x8_t*)&cb[(wc * 64 + n * 16 + lrow) * 32 + kg];
#pragma unroll
    for (int m = 0; m < 4; ++m)
#pragma unroll
      for (int n = 0; n < 4; ++n)
        acc[m][n] = __builtin_amdgcn_mfma_f32_16x16x32_bf16(af[m], bfr[n], acc[m][n], 0, 0, 0);
    __syncthreads();   // drains vmcnt(0): next buf ready; lgkm: cur reads done
    cur ^= 1;
  }
#pragma unroll
  for (int n = 0; n < 4; ++n) {
    int col = col0 + wc * 64 + n * 16 + lrow;
    float bv = bias[col];
#pragma unroll
    for (int m = 0; m < 4; ++m) {
#pragma unroll
      for (int j = 0; j < 4; ++j) {
        int row = row0 + wr * 64 + m * 16 + (lane >> 4) * 4 + j;
        float v = acc[m][n][j] + bv;
        if (ACT) v = mishf(v);
        C[(size_t)row * N + col] = f2b(v);
      }
    }
  }
}

// ---- start-flag dtype detection (int32 vs uint8) + nseg zeroing ----
__global__ void detect_start_mode(const unsigned int* __restrict__ w,
                                  int* __restrict__ mode, int* __restrict__ nseg) {
  if (threadIdx.x == 0 && blockIdx.x == 0) {
    int m = 0;
    for (int i = 0; i < 64; ++i)
      if (w[i] > 1u) m = 1;
    *mode = m;  // 1 = uint8, 0 = int32
    *nseg = 0;
  }
}
__device__ __forceinline__ int start_flag(const void* start, int mode, int t) {
  if (mode) return ((const unsigned char*)start)[t] != 0;
  return ((const int*)start)[t] != 0;
}

// ---- segment list: every t with (t==0 || start[t]) begins a segment ----
__global__ __launch_bounds__(256) void seg_build(
    const void* __restrict__ start, const int* __restrict__ mode_p,
    int* __restrict__ t0_raw, int* __restrict__ len_raw, int* __restrict__ nseg) {
  int t = blockIdx.x * blockDim.x + threadIdx.x;
  if (t >= T_STEPS) return;
  int mode = *mode_p;
  if (t != 0 && !start_flag(start, mode, t)) return;
  int len = 1;
  while (t + len < T_STEPS && !start_flag(start, mode, t + len)) ++len;
  int slot = atomicAdd(nseg, 1);
  t0_raw[slot] = t;
  len_raw[slot] = len;
}

// ---- counting sort by length (descending); counts[i] = #segments with len > i ----
__global__ __launch_bounds__(256) void seg_sort(
    const int* __restrict__ t0_raw, const int* __restrict__ len_raw,
    const int* __restrict__ nseg_p,
    int* __restrict__ t0s, int* __restrict__ len_s, int* __restrict__ counts) {
  __shared__ int hist[K_MAX + 2], off[K_MAX + 2];
  int tid = threadIdx.x;
  int n = *nseg_p;
  if (tid < K_MAX + 2) hist[tid] = 0;
  __syncthreads();
  for (int s = tid; s < n; s += 256)
    atomicAdd(&hist[min(len_raw[s], K_MAX + 1)], 1);
  __syncthreads();
  if (tid == 0) {
    int acc = 0;
    for (int b = K_MAX + 1; b >= 1; --b) { off[b] = acc; acc += hist[b]; }
    for (int i = 0; i <= K_MAX; ++i) {
      int c = 0;
      for (int b = i + 1; b <= K_MAX + 1; ++b) c += hist[b];
      counts[i] = c;
    }
  }
  __syncthreads();
  for (int s = tid; s < n; s += 256) {
    int pos = atomicAdd(&off[min(len_raw[s], K_MAX + 1)], 1);
    t0s[pos] = t0_raw[s];
    len_s[pos] = len_raw[s];
  }
}

// ---- hg0 = w_hh(f32) @ state0(f32): only segment containing t=0 needs a nonzero h ----
__global__ __launch_bounds__(256) void matvec0(
    const float* __restrict__ w_hh, const float* __restrict__ state0,
    float* __restrict__ hg0) {
  int g = threadIdx.x >> 4, l16 = threadIdx.x & 15;
  int row = blockIdx.x * 16 + g;
  const float* wr = w_hh + (size_t)row * D_REC;
  float s = 0.f;
#pragma unroll
  for (int i = 0; i < 16; ++i) {
    int c = (l16 + i * 16) * 4;
    float4 w4 = *(const float4*)&wr[c];
    float4 h4 = *(const float4*)&state0[c];
    s += w4.x * h4.x + w4.y * h4.y + w4.z * h4.z + w4.w * h4.w;
  }
#pragma unroll
  for (int o = 1; o < 16; o <<= 1) s += __shfl_xor(s, o);
  if (l16 == 0) hg0[row] = s;
}

// ---- iteration 0 gate: h_prev = state0 (seg at t=0, no reset) or 0 ----
__global__ __launch_bounds__(256) void gru_gate0(
    unsigned short* __restrict__ states, const unsigned short* __restrict__ igates,
    const void* __restrict__ start, const int* __restrict__ mode_p,
    const int* __restrict__ t0s, const int* __restrict__ nseg_p,
    const float* __restrict__ hg0, const float* __restrict__ state0,
    const float* __restrict__ b_n, float* __restrict__ Hf32,
    float* __restrict__ finals) {
  int p = blockIdx.x;
  if (p >= *nseg_p) return;
  int t0 = t0s[p];
  int mode = *mode_p;
  bool use_s0 = (t0 == 0) && !start_flag(start, mode, 0);
  size_t ib = (size_t)t0 * G3REC;
  for (int u = threadIdx.x; u < D_REC; u += 256) {
    float hp = use_s0 ? state0[u] : 0.f;
    float hr = use_s0 ? hg0[u] : 0.f;
    float hz = use_s0 ? hg0[D_REC + u] : 0.f;
    float hn = use_s0 ? hg0[2 * D_REC + u] : 0.f;
    float r = sigmf(b2f(igates[ib + u]) + hr);
    float z = sigmf(b2f(igates[ib + D_REC + u]) + hz);
    float n = tanhf(b2f(igates[ib + 2 * D_REC + u]) + r * (hn + b_n[u]));
    float hnew = n + z * (hp - n);
    if (p < HCAP) Hf32[(size_t)p * D_REC + u] = hnew;
    states[(size_t)t0 * D_REC + u] = f2b(hnew);
    if (t0 == T_STEPS - 1) finals[u] = hnew;
  }
}

// ---- fused wavefront iteration i>=1: hg GEMM (A gathered from states) + gate epilogue.
// Tile: 128 segments x 96 w_perm-rows (=32 units x 3 gates). 4 waves of 32x96.
// Double-buffered staging like gemm_tn_bf16.
__global__ __launch_bounds__(256) void gru_iter(
    unsigned short* __restrict__ states,
    const unsigned short* __restrict__ igates,
    const unsigned short* __restrict__ w_perm,
    const int* __restrict__ t0s, const int* __restrict__ counts,
    const float* __restrict__ b_n, float* __restrict__ Hf32,
    float* __restrict__ finals, int iter) {
  const int count = counts[iter];
  const int row0 = blockIdx.x * 128;
  if (row0 >= count) return;
  const int u0 = blockIdx.y * 32;
  const int col0 = u0 * 3;
  __shared__ __align__(16) float smem_f[128 * 98];        // 50176 B
  unsigned short* sb = (unsigned short*)smem_f;
  // a bufs: [0,4096),[4096,8192); b bufs: [8192,11264),[11264,14336) (elements)
  float* hgl = smem_f;                                    // [128][98] f32 (after K-loop)
  const int tid = threadIdx.x;
  const int lane = tid & 63, wave = tid >> 6;
  const int rA = tid >> 2, c8 = (tid & 3) * 8;
  int gA0 = (row0 + rA < count) ? (t0s[row0 + rA] + iter - 1) : (t0s[0] + iter - 1);
  int gA1 = (row0 + rA + 64 < count) ? (t0s[row0 + rA + 64] + iter - 1) : (t0s[0] + iter - 1);
  const unsigned short* srcA0 = states + (size_t)gA0 * D_REC + c8;
  const unsigned short* srcA1 = states + (size_t)gA1 * D_REC + c8;
  const unsigned short* srcB0 = w_perm + (size_t)(col0 + rA) * D_REC + c8;
  const unsigned short* srcB1 = w_perm + (size_t)(col0 + 64 + rA) * D_REC + c8; // waves 0,1
  const int so = wave * 512;
  auto stage = [&](int buf, int k0) {
    unsigned short* la = sb + buf * 4096 + so;
    unsigned short* lb = sb + 8192 + buf * 3072 + so;
    gload_lds16(srcA0 + k0, la);
    gload_lds16(srcA1 + k0, la + 2048);
    gload_lds16(srcB0 + k0, lb);
    if (wave < 2)
      gload_lds16(srcB1 + k0, lb + 2048);
  };
  f32x4_t acc[2][6] = {};
  const int lrow = lane & 15, kg = (lane >> 4) * 8;
  stage(0, 0);
  __syncthreads();
  int cur = 0;
  for (int t = 0; t < 32; ++t) {
    if (t + 1 < 32) stage(cur ^ 1, (t + 1) << 5);
    const unsigned short* ca = sb + cur * 4096;
    const unsigned short* cb = sb + 8192 + cur * 3072;
    bf16x8_t af[2], bfr[6];
#pragma unroll
    for (int m = 0; m < 2; ++m)
      af[m] = *(const bf16x8_t*)&ca[(wave * 32 + m * 16 + lrow) * 32 + kg];
#pragma unroll
    for (int n = 0; n < 6; ++n)
      bfr[n] = *(const bf16x8_t*)&cb[(n * 16 + lrow) * 32 + kg];
#pragma unroll
    for (int m = 0; m < 2; ++m)
#pragma unroll
      for (int n = 0; n < 6; ++n)
        acc[m][n] = __builtin_amdgcn_mfma_f32_16x16x32_bf16(af[m], bfr[n], acc[m][n], 0, 0, 0);
    __syncthreads();
    cur ^= 1;
  }
  // dump acc tile to LDS (row-local x 96 cols, stride 98 to dodge bank conflicts)
#pragma unroll
  for (int m = 0; m < 2; ++m)
#pragma unroll
    for (int n = 0; n < 6; ++n)
#pragma unroll
      for (int j = 0; j < 4; ++j) {
        int row = wave * 32 + m * 16 + (lane >> 4) * 4 + j;
        hgl[row * 98 + n * 16 + lrow] = acc[m][n][j];
      }
  __syncthreads();
  // gate epilogue: 128 segs x 32 units
  for (int idx = tid; idx < 128 * 32; idx += 256) {
    int pl = idx >> 5, ul = idx & 31;
    int p = row0 + pl;
    if (p >= count) continue;
    int t = t0s[p] + iter;
    int u = u0 + ul;
    float hr = hgl[pl * 98 + 3 * ul + 0];
    float hz = hgl[pl * 98 + 3 * ul + 1];
    float hn = hgl[pl * 98 + 3 * ul + 2];
    size_t ib = (size_t)t * G3REC;
    float hp = Hf32[(size_t)p * D_REC + u];
    float r = sigmf(b2f(igates[ib + u]) + hr);
    float z = sigmf(b2f(igates[ib + D_REC + u]) + hz);
    float n = tanhf(b2f(igates[ib + 2 * D_REC + u]) + r * (hn + b_n[u]));
    float hnew = n + z * (hp - n);
    Hf32[(size_t)p * D_REC + u] = hnew;
    states[(size_t)t * D_REC + u] = f2b(hnew);
    if (t == T_STEPS - 1) finals[u] = hnew;
  }
}

// ---- sequential tail for segments with len > K_MAX (w.h.p. none) ----
__global__ __launch_bounds__(256) void gru_cleanup(
    unsigned short* __restrict__ states, const unsigned short* __restrict__ igates,
    const unsigned short* __restrict__ w_perm,
    const int* __restrict__ t0s, const int* __restrict__ len_s,
    const int* __restrict__ counts, const float* __restrict__ b_n,
    const float* __restrict__ Hf32, float* __restrict__ finals) {
  int p = blockIdx.x;
  if (p >= counts[K_MAX]) return;  // segments with len > K_MAX (sorted first)
  int t0 = t0s[p], len = len_s[p];
  __shared__ float h[D_REC];
  __shared__ float hgl[G3REC];
  const int tid = threadIdx.x;
  for (int u = tid; u < D_REC; u += 256) h[u] = Hf32[(size_t)p * D_REC + u];
  __syncthreads();
  const int g = tid >> 4, l16 = tid & 15;
  for (int s = K_MAX; s < len; ++s) {
    int t = t0 + s;
    float hreg[64];
#pragma unroll
    for (int i = 0; i < 8; ++i) {
      float4 a = *(const float4*)&h[l16 * 8 + i * 128];
      float4 b = *(const float4*)&h[l16 * 8 + i * 128 + 4];
      hreg[i * 8 + 0] = a.x; hreg[i * 8 + 1] = a.y; hreg[i * 8 + 2] = a.z; hreg[i * 8 + 3] = a.w;
      hreg[i * 8 + 4] = b.x; hreg[i * 8 + 5] = b.y; hreg[i * 8 + 6] = b.z; hreg[i * 8 + 7] = b.w;
    }
    for (int row = g; row < G3REC; row += 16) {
      const unsigned short* wrow = w_perm + (size_t)row * D_REC;
      float sum = 0.f;
#pragma unroll
      for (int i = 0; i < 8; ++i) {
        bf16x8_t wv = *(const bf16x8_t*)&wrow[l16 * 8 + i * 128];
#pragma unroll
        for (int j = 0; j < 8; ++j)
          sum += b2f((unsigned short)wv[j]) * hreg[i * 8 + j];
      }
#pragma unroll
      for (int o = 1; o < 16; o <<= 1) sum += __shfl_xor(sum, o);
      if (l16 == 0) hgl[row] = sum;
    }
    __syncthreads();
    size_t ib = (size_t)t * G3REC;
    for (int u = tid; u < D_REC; u += 256) {
      float r = sigmf(b2f(igates[ib + u]) + hgl[3 * u + 0]);
      float z = sigmf(b2f(igates[ib + D_REC + u]) + hgl[3 * u + 1]);
      float n = tanhf(b2f(igates[ib + 2 * D_REC + u]) + r * (hgl[3 * u + 2] + b_n[u]));
      float hnew = n + z * (h[u] - n);
      h[u] = hnew;
      states[(size_t)t * D_REC + u] = f2b(hnew);
      if (t == T_STEPS - 1) finals[u] = hnew;
    }
    __syncthreads();
  }
}

// ---- heads + dueling epilogue (one wave per timestep) ----
__global__ __launch_bounds__(64) void heads_kernel(
    const unsigned short* __restrict__ y,
    const float* __restrict__ Wv, const float* __restrict__ bv,
    const float* __restrict__ Wa, const float* __restrict__ ba,
    const float* __restrict__ Ws, const float* __restrict__ bs,
    float* __restrict__ q) {
  const int t = blockIdx.x, lane = threadIdx.x;
  const unsigned short* yr = y + (size_t)t * D_MLP;
  float yv[16];
#pragma unroll
  for (int c = 0; c < 2; ++c) {
    bf16x8_t v = *(const bf16x8_t*)&yr[lane * 16 + c * 8];
#pragma unroll
    for (int j = 0; j < 8; ++j) yv[c * 8 + j] = b2f((unsigned short)v[j]);
  }
  float mine = 0.f;
  for (int o = 0; o < 18; ++o) {
    const float* w = (o < 16) ? (Wa + (size_t)o * D_MLP) : (o == 16 ? Wv : Ws);
    float s = 0.f;
#pragma unroll
    for (int c = 0; c < 4; ++c) {
      float4 wv = *(const float4*)&w[lane * 16 + c * 4];
      s += wv.x * yv[c * 4 + 0] + wv.y * yv[c * 4 + 1] +
           wv.z * yv[c * 4 + 2] + wv.w * yv[c * 4 + 3];
    }
#pragma unroll
    for (int off = 1; off < 64; off <<= 1) s += __shfl_xor(s, off);
    if (lane == o) mine = s;
  }
  if (lane < 16) mine += ba[lane];
  else if (lane == 16) mine += bv[0];
  else if (lane == 17) mine += bs[0];
  float a = (lane < 16) ? mine : 0.f;
  float ss = a * a;
#pragma unroll
  for (int off = 1; off < 64; off <<= 1) ss += __shfl_xor(ss, off);
  float an = a / (1e-6f + sqrtf(ss));
  float ms = (lane < 16) ? an : 0.f;
#pragma unroll
  for (int off = 1; off < 64; off <<= 1) ms += __shfl_xor(ms, off);
  float adv = an - ms * (1.f / 16.f);
  float val = __shfl(mine, 16);
  float sc = __shfl(mine, 17);
  if (lane < 16) q[(size_t)t * D_ACT + lane] = val + sc * adv;
}

extern "C" void kernel_launch(void* const* d_in, const int* in_sizes, int n_in,
                              void* d_out, int out_size, void* d_ws, size_t ws_size,
                              hipStream_t stream) {
  const float* x      = (const float*)d_in[0];
  const float* state0 = (const float*)d_in[1];
  const void*  start  = d_in[2];
  const float* W_pre  = (const float*)d_in[3];
  const float* b_pre  = (const float*)d_in[4];
  const float* w_ih   = (const float*)d_in[5];
  const float* w_hh   = (const float*)d_in[6];
  const float* b_ih   = (const float*)d_in[7];
  const float* b_n    = (const float*)d_in[8];
  const float* W1     = (const float*)d_in[9];
  const float* b1     = (const float*)d_in[10];
  const float* W2     = (const float*)d_in[11];
  const float* b2     = (const float*)d_in[12];
  const float* Wv     = (const float*)d_in[13];
  const float* bv     = (const float*)d_in[14];
  const float* Wa     = (const float*)d_in[15];
  const float* ba     = (const float*)d_in[16];
  const float* Ws     = (const float*)d_in[17];
  const float* bs     = (const float*)d_in[18];

  // workspace layout (phases: A=pre/igates, B=scan, C=post). Peak < 99 MB.
  char* ws = (char*)d_ws;
  const size_t MB = 1ull << 20;
  unsigned short* igates = (unsigned short*)(ws);
  unsigned short* y2     = igates;
  unsigned short* xp     = (unsigned short*)(ws + 48 * MB);
  float*          Hf32   = (float*)(ws + 48 * MB);
  unsigned short* y1     = xp;
  unsigned short* states = (unsigned short*)(ws + 66 * MB);
  unsigned short* x_bf   = (unsigned short*)(ws + 82 * MB);
  unsigned short* w_perm = (unsigned short*)(ws + 82 * MB);
  unsigned short* Wpre_bf= (unsigned short*)(ws + 88 * MB);
  unsigned short* wih_bf = (unsigned short*)(ws + 88 * MB + 512 * 1024);
  unsigned short* W1_bf  = (unsigned short*)(ws + 94 * MB + 512 * 1024);
  unsigned short* W2_bf  = (unsigned short*)(ws + 96 * MB + 512 * 1024);
  char* seg = ws + 98 * MB + 512 * 1024;
  int* t0_raw  = (int*)(seg);
  int* len_raw = (int*)(seg + 32768);
  int* t0s     = (int*)(seg + 65536);
  int* len_s   = (int*)(seg + 98304);
  int* counts  = (int*)(seg + 131072);
  int* nseg_p  = (int*)(seg + 131072 + 128);
  int* mode_p  = (int*)(seg + 131072 + 192);
  float* hg0   = (float*)(seg + 131072 + 256);
  float* qout   = (float*)d_out;
  float* finals = qout + (size_t)T_STEPS * D_ACT;

  detect_start_mode<<<1, 64, 0, stream>>>((const unsigned int*)start, mode_p, nseg_p);
  cvt_f32_bf16<<<512, 256, 0, stream>>>(x,     x_bf,    (T_STEPS * D_OBS) / 4);
  cvt_f32_bf16<<<256, 256, 0, stream>>>(W_pre, Wpre_bf, (D_MLP * D_OBS) / 4);
  cvt_f32_bf16<<<768, 256, 0, stream>>>(w_ih,  wih_bf,  (G3REC * D_MLP) / 4);
  cvt_f32_bf16<<<512, 256, 0, stream>>>(W1,    W1_bf,   (D_MLP * D_REC) / 4);
  cvt_f32_bf16<<<512, 256, 0, stream>>>(W2,    W2_bf,   (D_MLP * D_MLP) / 4);
  seg_build<<<32, 256, 0, stream>>>(start, mode_p, t0_raw, len_raw, nseg_p);
  seg_sort<<<1, 256, 0, stream>>>(t0_raw, len_raw, nseg_p, t0s, len_s, counts);
  matvec0<<<192, 256, 0, stream>>>(w_hh, state0, hg0);

  // pre-MLP, then w_hh permute-convert (reuses x_bf region), then igates GEMM
  gemm_tn_bf16<1><<<dim3(64, 8), 256, 0, stream>>>(x_bf, Wpre_bf, b_pre, xp, T_STEPS, D_MLP, D_OBS);
  cvt_whh_perm<<<3072, 256, 0, stream>>>(w_hh, w_perm);
  gemm_tn_bf16<0><<<dim3(64, 24), 256, 0, stream>>>(xp, wih_bf, b_ih, igates, T_STEPS, G3REC, D_MLP);

  // wavefront scan
  gru_gate0<<<8192, 256, 0, stream>>>(states, igates, start, mode_p, t0s, nseg_p,
                                      hg0, state0, b_n, Hf32, finals);
  for (int i = 1; i < K_MAX; ++i) {
    int mt = (8192 / (i + 1) + 127) / 128;  // count_i <= 8192/(i+1)
    gru_iter<<<dim3(mt, 32), 256, 0, stream>>>(states, igates, w_perm, t0s, counts,
                                               b_n, Hf32, finals, i);
  }
  gru_cleanup<<<512, 256, 0, stream>>>(states, igates, w_perm, t0s, len_s, counts,
                                       b_n, Hf32, finals);

  // post MLP + heads
  gemm_tn_bf16<1><<<dim3(64, 8), 256, 0, stream>>>(states, W1_bf, b1, y1, T_STEPS, D_MLP, D_REC);
  gemm_tn_bf16<1><<<dim3(64, 8), 256, 0, stream>>>(y1, W2_bf, b2, y2, T_STEPS, D_MLP, D_MLP);
  heads_kernel<<<8192, 64, 0, stream>>>(y2, Wv, bv, Wa, ba, Ws, bs, qout);
}

// Round 6
// 647.097 us; speedup vs baseline: 13.1166x; 1.1385x over previous
//
#include <hip/hip_runtime.h>
#include <hip/hip_bf16.h>
#include <cstdint>
#include <cstddef>

#define T_STEPS 8192
#define D_OBS 256
#define D_ACT 16
#define D_MLP 1024
#define D_REC 1024
#define G3REC 3072
#define K_MAX 20          // wavefront iterations 0..K_MAX-1; cleanup handles len > K_MAX
#define HCAP 4608         // Hf32 row capacity (nseg ~ 4096 +/- 45; 11-sigma headroom)

typedef short bf16x8_t __attribute__((ext_vector_type(8)));
typedef float f32x4_t __attribute__((ext_vector_type(4)));

__device__ __forceinline__ float b2f(unsigned short u) {
  union { uint32_t i; float f; } v; v.i = ((uint32_t)u) << 16; return v.f;
}
__device__ __forceinline__ unsigned short f2b(float f) {
  union { float f; uint32_t i; } v; v.f = f;
  uint32_t r = v.i + 0x7fffu + ((v.i >> 16) & 1u);
  return (unsigned short)(r >> 16);
}
__device__ __forceinline__ float mishf(float v) {
  float sp = (v > 15.f) ? v : log1pf(expf(v));
  return v * tanhf(sp);
}
__device__ __forceinline__ float sigmf(float x) { return 1.f / (1.f + expf(-x)); }

// async global->LDS, 16B per lane; LDS dest = wave-uniform base + lane*16.
__device__ __forceinline__ void gload_lds16(const void* g, void* l) {
  __builtin_amdgcn_global_load_lds((const __attribute__((address_space(1))) void*)g,
                                   (__attribute__((address_space(3))) void*)l, 16, 0, 0);
}

// ---- f32 -> bf16 conversion ----
__global__ __launch_bounds__(256) void cvt_f32_bf16(
    const float* __restrict__ in, unsigned short* __restrict__ out, int n4) {
  int stride = gridDim.x * blockDim.x;
  for (int j = blockIdx.x * blockDim.x + threadIdx.x; j < n4; j += stride) {
    float4 v = ((const float4*)in)[j];
    ushort4 o;
    o.x = f2b(v.x); o.y = f2b(v.y); o.z = f2b(v.z); o.w = f2b(v.w);
    ((ushort4*)out)[j] = o;
  }
}

// w_hh [3072,1024] f32 -> w_perm bf16 with row permutation: out row 3u+g = in row g*1024+u.
__global__ __launch_bounds__(256) void cvt_whh_perm(
    const float* __restrict__ in, unsigned short* __restrict__ out) {
  int r = blockIdx.x;                 // original row
  int g = r >> 10, u = r & 1023;
  unsigned short* dst = out + (size_t)(u * 3 + g) * D_REC;
  const float* src = in + (size_t)r * D_REC;
  for (int c = threadIdx.x * 4; c < D_REC; c += 1024) {
    float4 v = *(const float4*)&src[c];
    ushort4 o; o.x = f2b(v.x); o.y = f2b(v.y); o.z = f2b(v.z); o.w = f2b(v.w);
    *(ushort4*)&dst[c] = o;
  }
}

// C[M,N] = act(A[M,K] @ B[N,K]^T + bias[N]); A,B,C bf16, bias f32, f32 accum.
// 64x64 tile, BK=32, 4 waves (2x2 of 32x32), dbuf global_load_lds.
// Small tile -> 2048+ blocks = 8 blocks/CU = 32 waves/CU: latency hidden by TLP
// (m92-class config; the 128^2 tile was stuck at ~2 blocks/CU = 90-115 TF at N=1024).
template <int ACT>
__global__ __launch_bounds__(256) void gemm_tn_bf16(
    const unsigned short* __restrict__ A,
    const unsigned short* __restrict__ B,
    const float* __restrict__ bias,
    unsigned short* __restrict__ C,
    int M, int N, int K) {
  __shared__ unsigned short lds_a[2][64 * 32];
  __shared__ unsigned short lds_b[2][64 * 32];
  const int tid = threadIdx.x;
  const int lane = tid & 63;
  const int wave = tid >> 6;
  const int wr = wave >> 1, wc = wave & 1;
  const int row0 = blockIdx.x * 64, col0 = blockIdx.y * 64;
  f32x4_t acc[2][2] = {};
  const int lrow = lane & 15, kg = (lane >> 4) * 8;
  // staging: chunk tid covers LDS elements tid*8..tid*8+7 of a [64][32] tile;
  // global row = tid>>2, cols (tid&3)*8.. ; per-wave LDS base is uniform.
  const int r = tid >> 2, c8 = (tid & 3) * 8;
  const unsigned short* gA = &A[(size_t)(row0 + r) * K + c8];
  const unsigned short* gB = &B[(size_t)(col0 + r) * K + c8];
  const int so = wave * 512;  // per-wave LDS staging base (elements)
  auto stage = [&](int buf, int k0) {
    gload_lds16(gA + k0, &lds_a[buf][so]);
    gload_lds16(gB + k0, &lds_b[buf][so]);
  };
  const int nk = K >> 5;
  stage(0, 0);
  __syncthreads();
  int cur = 0;
  for (int t = 0; t < nk; ++t) {
    if (t + 1 < nk) stage(cur ^ 1, (t + 1) << 5);
    bf16x8_t af[2], bfr[2];
#pragma unroll
    for (int m = 0; m < 2; ++m)
      af[m] = *(const bf16x8_t*)&lds_a[cur][(wr * 32 + m * 16 + lrow) * 32 + kg];
#pragma unroll
    for (int n = 0; n < 2; ++n)
      bfr[n] = *(const bf16x8_t*)&lds_b[cur][(wc * 32 + n * 16 + lrow) * 32 + kg];
#pragma unroll
    for (int m = 0; m < 2; ++m)
#pragma unroll
      for (int n = 0; n < 2; ++n)
        acc[m][n] = __builtin_amdgcn_mfma_f32_16x16x32_bf16(af[m], bfr[n], acc[m][n], 0, 0, 0);
    __syncthreads();   // drains vmcnt(0): next buf staged; lgkm: cur reads done
    cur ^= 1;
  }
  // C/D layout (verified m89/m91): col = lane&15, row = (lane>>4)*4 + j
#pragma unroll
  for (int n = 0; n < 2; ++n) {
    int col = col0 + wc * 32 + n * 16 + lrow;
    float bv = bias[col];
#pragma unroll
    for (int m = 0; m < 2; ++m) {
#pragma unroll
      for (int j = 0; j < 4; ++j) {
        int row = row0 + wr * 32 + m * 16 + (lane >> 4) * 4 + j;
        float v = acc[m][n][j] + bv;
        if (ACT) v = mishf(v);
        C[(size_t)row * N + col] = f2b(v);
      }
    }
  }
}

// ---- start-flag dtype detection (int32 vs uint8) + nseg zeroing ----
__global__ void detect_start_mode(const unsigned int* __restrict__ w,
                                  int* __restrict__ mode, int* __restrict__ nseg) {
  if (threadIdx.x == 0 && blockIdx.x == 0) {
    int m = 0;
    for (int i = 0; i < 64; ++i)
      if (w[i] > 1u) m = 1;
    *mode = m;  // 1 = uint8, 0 = int32
    *nseg = 0;
  }
}
__device__ __forceinline__ int start_flag(const void* start, int mode, int t) {
  if (mode) return ((const unsigned char*)start)[t] != 0;
  return ((const int*)start)[t] != 0;
}

// ---- segment list: every t with (t==0 || start[t]) begins a segment ----
__global__ __launch_bounds__(256) void seg_build(
    const void* __restrict__ start, const int* __restrict__ mode_p,
    int* __restrict__ t0_raw, int* __restrict__ len_raw, int* __restrict__ nseg) {
  int t = blockIdx.x * blockDim.x + threadIdx.x;
  if (t >= T_STEPS) return;
  int mode = *mode_p;
  if (t != 0 && !start_flag(start, mode, t)) return;
  int len = 1;
  while (t + len < T_STEPS && !start_flag(start, mode, t + len)) ++len;
  int slot = atomicAdd(nseg, 1);
  t0_raw[slot] = t;
  len_raw[slot] = len;
}

// ---- counting sort by length (descending); counts[i] = #segments with len > i ----
__global__ __launch_bounds__(256) void seg_sort(
    const int* __restrict__ t0_raw, const int* __restrict__ len_raw,
    const int* __restrict__ nseg_p,
    int* __restrict__ t0s, int* __restrict__ len_s, int* __restrict__ counts) {
  __shared__ int hist[K_MAX + 2], off[K_MAX + 2];
  int tid = threadIdx.x;
  int n = *nseg_p;
  if (tid < K_MAX + 2) hist[tid] = 0;
  __syncthreads();
  for (int s = tid; s < n; s += 256)
    atomicAdd(&hist[min(len_raw[s], K_MAX + 1)], 1);
  __syncthreads();
  if (tid == 0) {
    int acc = 0;
    for (int b = K_MAX + 1; b >= 1; --b) { off[b] = acc; acc += hist[b]; }
    for (int i = 0; i <= K_MAX; ++i) {
      int c = 0;
      for (int b = i + 1; b <= K_MAX + 1; ++b) c += hist[b];
      counts[i] = c;
    }
  }
  __syncthreads();
  for (int s = tid; s < n; s += 256) {
    int pos = atomicAdd(&off[min(len_raw[s], K_MAX + 1)], 1);
    t0s[pos] = t0_raw[s];
    len_s[pos] = len_raw[s];
  }
}

// ---- hg0 = w_hh(f32) @ state0(f32): only segment containing t=0 needs a nonzero h ----
__global__ __launch_bounds__(256) void matvec0(
    const float* __restrict__ w_hh, const float* __restrict__ state0,
    float* __restrict__ hg0) {
  int g = threadIdx.x >> 4, l16 = threadIdx.x & 15;
  int row = blockIdx.x * 16 + g;
  const float* wr = w_hh + (size_t)row * D_REC;
  float s = 0.f;
#pragma unroll
  for (int i = 0; i < 16; ++i) {
    int c = (l16 + i * 16) * 4;
    float4 w4 = *(const float4*)&wr[c];
    float4 h4 = *(const float4*)&state0[c];
    s += w4.x * h4.x + w4.y * h4.y + w4.z * h4.z + w4.w * h4.w;
  }
#pragma unroll
  for (int o = 1; o < 16; o <<= 1) s += __shfl_xor(s, o);
  if (l16 == 0) hg0[row] = s;
}

// ---- iteration 0 gate: h_prev = state0 (seg at t=0, no reset) or 0 ----
__global__ __launch_bounds__(256) void gru_gate0(
    unsigned short* __restrict__ states, const unsigned short* __restrict__ igates,
    const void* __restrict__ start, const int* __restrict__ mode_p,
    const int* __restrict__ t0s, const int* __restrict__ nseg_p,
    const float* __restrict__ hg0, const float* __restrict__ state0,
    const float* __restrict__ b_n, float* __restrict__ Hf32,
    float* __restrict__ finals) {
  int p = blockIdx.x;
  if (p >= *nseg_p) return;
  int t0 = t0s[p];
  int mode = *mode_p;
  bool use_s0 = (t0 == 0) && !start_flag(start, mode, 0);
  size_t ib = (size_t)t0 * G3REC;
  for (int u = threadIdx.x; u < D_REC; u += 256) {
    float hp = use_s0 ? state0[u] : 0.f;
    float hr = use_s0 ? hg0[u] : 0.f;
    float hz = use_s0 ? hg0[D_REC + u] : 0.f;
    float hn = use_s0 ? hg0[2 * D_REC + u] : 0.f;
    float r = sigmf(b2f(igates[ib + u]) + hr);
    float z = sigmf(b2f(igates[ib + D_REC + u]) + hz);
    float n = tanhf(b2f(igates[ib + 2 * D_REC + u]) + r * (hn + b_n[u]));
    float hnew = n + z * (hp - n);
    if (p < HCAP) Hf32[(size_t)p * D_REC + u] = hnew;
    states[(size_t)t0 * D_REC + u] = f2b(hnew);
    if (t0 == T_STEPS - 1) finals[u] = hnew;
  }
}

// ---- fused wavefront iteration i>=1: hg GEMM (A gathered from states) + gate epilogue.
// Tile: 128 segments x 96 w_perm-rows (=32 units x 3 gates). 4 waves of 32x96.
// Double-buffered staging.
__global__ __launch_bounds__(256) void gru_iter(
    unsigned short* __restrict__ states,
    const unsigned short* __restrict__ igates,
    const unsigned short* __restrict__ w_perm,
    const int* __restrict__ t0s, const int* __restrict__ counts,
    const float* __restrict__ b_n, float* __restrict__ Hf32,
    float* __restrict__ finals, int iter) {
  const int count = counts[iter];
  const int row0 = blockIdx.x * 128;
  if (row0 >= count) return;
  const int u0 = blockIdx.y * 32;
  const int col0 = u0 * 3;
  __shared__ __align__(16) float smem_f[128 * 98];        // 50176 B
  unsigned short* sb = (unsigned short*)smem_f;
  // a bufs: [0,4096),[4096,8192); b bufs: [8192,11264),[11264,14336) (elements)
  float* hgl = smem_f;                                    // [128][98] f32 (after K-loop)
  const int tid = threadIdx.x;
  const int lane = tid & 63, wave = tid >> 6;
  const int rA = tid >> 2, c8 = (tid & 3) * 8;
  int gA0 = (row0 + rA < count) ? (t0s[row0 + rA] + iter - 1) : (t0s[0] + iter - 1);
  int gA1 = (row0 + rA + 64 < count) ? (t0s[row0 + rA + 64] + iter - 1) : (t0s[0] + iter - 1);
  const unsigned short* srcA0 = states + (size_t)gA0 * D_REC + c8;
  const unsigned short* srcA1 = states + (size_t)gA1 * D_REC + c8;
  const unsigned short* srcB0 = w_perm + (size_t)(col0 + rA) * D_REC + c8;
  const unsigned short* srcB1 = w_perm + (size_t)(col0 + 64 + rA) * D_REC + c8; // waves 0,1
  const int so = wave * 512;
  auto stage = [&](int buf, int k0) {
    unsigned short* la = sb + buf * 4096 + so;
    unsigned short* lb = sb + 8192 + buf * 3072 + so;
    gload_lds16(srcA0 + k0, la);
    gload_lds16(srcA1 + k0, la + 2048);
    gload_lds16(srcB0 + k0, lb);
    if (wave < 2)
      gload_lds16(srcB1 + k0, lb + 2048);
  };
  f32x4_t acc[2][6] = {};
  const int lrow = lane & 15, kg = (lane >> 4) * 8;
  stage(0, 0);
  __syncthreads();
  int cur = 0;
  for (int t = 0; t < 32; ++t) {
    if (t + 1 < 32) stage(cur ^ 1, (t + 1) << 5);
    const unsigned short* ca = sb + cur * 4096;
    const unsigned short* cb = sb + 8192 + cur * 3072;
    bf16x8_t af[2], bfr[6];
#pragma unroll
    for (int m = 0; m < 2; ++m)
      af[m] = *(const bf16x8_t*)&ca[(wave * 32 + m * 16 + lrow) * 32 + kg];
#pragma unroll
    for (int n = 0; n < 6; ++n)
      bfr[n] = *(const bf16x8_t*)&cb[(n * 16 + lrow) * 32 + kg];
#pragma unroll
    for (int m = 0; m < 2; ++m)
#pragma unroll
      for (int n = 0; n < 6; ++n)
        acc[m][n] = __builtin_amdgcn_mfma_f32_16x16x32_bf16(af[m], bfr[n], acc[m][n], 0, 0, 0);
    __syncthreads();
    cur ^= 1;
  }
  // dump acc tile to LDS (row-local x 96 cols, stride 98 to dodge bank conflicts)
#pragma unroll
  for (int m = 0; m < 2; ++m)
#pragma unroll
    for (int n = 0; n < 6; ++n)
#pragma unroll
      for (int j = 0; j < 4; ++j) {
        int row = wave * 32 + m * 16 + (lane >> 4) * 4 + j;
        hgl[row * 98 + n * 16 + lrow] = acc[m][n][j];
      }
  __syncthreads();
  // gate epilogue: 128 segs x 32 units
  for (int idx = tid; idx < 128 * 32; idx += 256) {
    int pl = idx >> 5, ul = idx & 31;
    int p = row0 + pl;
    if (p >= count) continue;
    int t = t0s[p] + iter;
    int u = u0 + ul;
    float hr = hgl[pl * 98 + 3 * ul + 0];
    float hz = hgl[pl * 98 + 3 * ul + 1];
    float hn = hgl[pl * 98 + 3 * ul + 2];
    size_t ib = (size_t)t * G3REC;
    float hp = Hf32[(size_t)p * D_REC + u];
    float r = sigmf(b2f(igates[ib + u]) + hr);
    float z = sigmf(b2f(igates[ib + D_REC + u]) + hz);
    float n = tanhf(b2f(igates[ib + 2 * D_REC + u]) + r * (hn + b_n[u]));
    float hnew = n + z * (hp - n);
    Hf32[(size_t)p * D_REC + u] = hnew;
    states[(size_t)t * D_REC + u] = f2b(hnew);
    if (t == T_STEPS - 1) finals[u] = hnew;
  }
}

// ---- sequential tail for segments with len > K_MAX (w.h.p. none) ----
__global__ __launch_bounds__(256) void gru_cleanup(
    unsigned short* __restrict__ states, const unsigned short* __restrict__ igates,
    const unsigned short* __restrict__ w_perm,
    const int* __restrict__ t0s, const int* __restrict__ len_s,
    const int* __restrict__ counts, const float* __restrict__ b_n,
    const float* __restrict__ Hf32, float* __restrict__ finals) {
  int p = blockIdx.x;
  if (p >= counts[K_MAX]) return;  // segments with len > K_MAX (sorted first)
  int t0 = t0s[p], len = len_s[p];
  __shared__ float h[D_REC];
  __shared__ float hgl[G3REC];
  const int tid = threadIdx.x;
  for (int u = tid; u < D_REC; u += 256) h[u] = Hf32[(size_t)p * D_REC + u];
  __syncthreads();
  const int g = tid >> 4, l16 = tid & 15;
  for (int s = K_MAX; s < len; ++s) {
    int t = t0 + s;
    float hreg[64];
#pragma unroll
    for (int i = 0; i < 8; ++i) {
      float4 a = *(const float4*)&h[l16 * 8 + i * 128];
      float4 b = *(const float4*)&h[l16 * 8 + i * 128 + 4];
      hreg[i * 8 + 0] = a.x; hreg[i * 8 + 1] = a.y; hreg[i * 8 + 2] = a.z; hreg[i * 8 + 3] = a.w;
      hreg[i * 8 + 4] = b.x; hreg[i * 8 + 5] = b.y; hreg[i * 8 + 6] = b.z; hreg[i * 8 + 7] = b.w;
    }
    for (int row = g; row < G3REC; row += 16) {
      const unsigned short* wrow = w_perm + (size_t)row * D_REC;
      float sum = 0.f;
#pragma unroll
      for (int i = 0; i < 8; ++i) {
        bf16x8_t wv = *(const bf16x8_t*)&wrow[l16 * 8 + i * 128];
#pragma unroll
        for (int j = 0; j < 8; ++j)
          sum += b2f((unsigned short)wv[j]) * hreg[i * 8 + j];
      }
#pragma unroll
      for (int o = 1; o < 16; o <<= 1) sum += __shfl_xor(sum, o);
      if (l16 == 0) hgl[row] = sum;
    }
    __syncthreads();
    size_t ib = (size_t)t * G3REC;
    for (int u = tid; u < D_REC; u += 256) {
      float r = sigmf(b2f(igates[ib + u]) + hgl[3 * u + 0]);
      float z = sigmf(b2f(igates[ib + D_REC + u]) + hgl[3 * u + 1]);
      float n = tanhf(b2f(igates[ib + 2 * D_REC + u]) + r * (hgl[3 * u + 2] + b_n[u]));
      float hnew = n + z * (h[u] - n);
      h[u] = hnew;
      states[(size_t)t * D_REC + u] = f2b(hnew);
      if (t == T_STEPS - 1) finals[u] = hnew;
    }
    __syncthreads();
  }
}

// ---- heads + dueling epilogue (one wave per timestep) ----
__global__ __launch_bounds__(64) void heads_kernel(
    const unsigned short* __restrict__ y,
    const float* __restrict__ Wv, const float* __restrict__ bv,
    const float* __restrict__ Wa, const float* __restrict__ ba,
    const float* __restrict__ Ws, const float* __restrict__ bs,
    float* __restrict__ q) {
  const int t = blockIdx.x, lane = threadIdx.x;
  const unsigned short* yr = y + (size_t)t * D_MLP;
  float yv[16];
#pragma unroll
  for (int c = 0; c < 2; ++c) {
    bf16x8_t v = *(const bf16x8_t*)&yr[lane * 16 + c * 8];
#pragma unroll
    for (int j = 0; j < 8; ++j) yv[c * 8 + j] = b2f((unsigned short)v[j]);
  }
  float mine = 0.f;
  for (int o = 0; o < 18; ++o) {
    const float* w = (o < 16) ? (Wa + (size_t)o * D_MLP) : (o == 16 ? Wv : Ws);
    float s = 0.f;
#pragma unroll
    for (int c = 0; c < 4; ++c) {
      float4 wv = *(const float4*)&w[lane * 16 + c * 4];
      s += wv.x * yv[c * 4 + 0] + wv.y * yv[c * 4 + 1] +
           wv.z * yv[c * 4 + 2] + wv.w * yv[c * 4 + 3];
    }
#pragma unroll
    for (int off = 1; off < 64; off <<= 1) s += __shfl_xor(s, off);
    if (lane == o) mine = s;
  }
  if (lane < 16) mine += ba[lane];
  else if (lane == 16) mine += bv[0];
  else if (lane == 17) mine += bs[0];
  float a = (lane < 16) ? mine : 0.f;
  float ss = a * a;
#pragma unroll
  for (int off = 1; off < 64; off <<= 1) ss += __shfl_xor(ss, off);
  float an = a / (1e-6f + sqrtf(ss));
  float ms = (lane < 16) ? an : 0.f;
#pragma unroll
  for (int off = 1; off < 64; off <<= 1) ms += __shfl_xor(ms, off);
  float adv = an - ms * (1.f / 16.f);
  float val = __shfl(mine, 16);
  float sc = __shfl(mine, 17);
  if (lane < 16) q[(size_t)t * D_ACT + lane] = val + sc * adv;
}

extern "C" void kernel_launch(void* const* d_in, const int* in_sizes, int n_in,
                              void* d_out, int out_size, void* d_ws, size_t ws_size,
                              hipStream_t stream) {
  const float* x      = (const float*)d_in[0];
  const float* state0 = (const float*)d_in[1];
  const void*  start  = d_in[2];
  const float* W_pre  = (const float*)d_in[3];
  const float* b_pre  = (const float*)d_in[4];
  const float* w_ih   = (const float*)d_in[5];
  const float* w_hh   = (const float*)d_in[6];
  const float* b_ih   = (const float*)d_in[7];
  const float* b_n    = (const float*)d_in[8];
  const float* W1     = (const float*)d_in[9];
  const float* b1     = (const float*)d_in[10];
  const float* W2     = (const float*)d_in[11];
  const float* b2     = (const float*)d_in[12];
  const float* Wv     = (const float*)d_in[13];
  const float* bv     = (const float*)d_in[14];
  const float* Wa     = (const float*)d_in[15];
  const float* ba     = (const float*)d_in[16];
  const float* Ws     = (const float*)d_in[17];
  const float* bs     = (const float*)d_in[18];

  // workspace layout (phases: A=pre/igates, B=scan, C=post). Peak < 99 MB.
  char* ws = (char*)d_ws;
  const size_t MB = 1ull << 20;
  unsigned short* igates = (unsigned short*)(ws);
  unsigned short* y2     = igates;
  unsigned short* xp     = (unsigned short*)(ws + 48 * MB);
  float*          Hf32   = (float*)(ws + 48 * MB);
  unsigned short* y1     = xp;
  unsigned short* states = (unsigned short*)(ws + 66 * MB);
  unsigned short* x_bf   = (unsigned short*)(ws + 82 * MB);
  unsigned short* w_perm = (unsigned short*)(ws + 82 * MB);
  unsigned short* Wpre_bf= (unsigned short*)(ws + 88 * MB);
  unsigned short* wih_bf = (unsigned short*)(ws + 88 * MB + 512 * 1024);
  unsigned short* W1_bf  = (unsigned short*)(ws + 94 * MB + 512 * 1024);
  unsigned short* W2_bf  = (unsigned short*)(ws + 96 * MB + 512 * 1024);
  char* seg = ws + 98 * MB + 512 * 1024;
  int* t0_raw  = (int*)(seg);
  int* len_raw = (int*)(seg + 32768);
  int* t0s     = (int*)(seg + 65536);
  int* len_s   = (int*)(seg + 98304);
  int* counts  = (int*)(seg + 131072);
  int* nseg_p  = (int*)(seg + 131072 + 128);
  int* mode_p  = (int*)(seg + 131072 + 192);
  float* hg0   = (float*)(seg + 131072 + 256);
  float* qout   = (float*)d_out;
  float* finals = qout + (size_t)T_STEPS * D_ACT;

  detect_start_mode<<<1, 64, 0, stream>>>((const unsigned int*)start, mode_p, nseg_p);
  cvt_f32_bf16<<<512, 256, 0, stream>>>(x,     x_bf,    (T_STEPS * D_OBS) / 4);
  cvt_f32_bf16<<<256, 256, 0, stream>>>(W_pre, Wpre_bf, (D_MLP * D_OBS) / 4);
  cvt_f32_bf16<<<768, 256, 0, stream>>>(w_ih,  wih_bf,  (G3REC * D_MLP) / 4);
  cvt_f32_bf16<<<512, 256, 0, stream>>>(W1,    W1_bf,   (D_MLP * D_REC) / 4);
  cvt_f32_bf16<<<512, 256, 0, stream>>>(W2,    W2_bf,   (D_MLP * D_MLP) / 4);
  seg_build<<<32, 256, 0, stream>>>(start, mode_p, t0_raw, len_raw, nseg_p);
  seg_sort<<<1, 256, 0, stream>>>(t0_raw, len_raw, nseg_p, t0s, len_s, counts);
  matvec0<<<192, 256, 0, stream>>>(w_hh, state0, hg0);

  // pre-MLP, then w_hh permute-convert, then igates GEMM
  gemm_tn_bf16<1><<<dim3(128, 16), 256, 0, stream>>>(x_bf, Wpre_bf, b_pre, xp, T_STEPS, D_MLP, D_OBS);
  cvt_whh_perm<<<3072, 256, 0, stream>>>(w_hh, w_perm);
  gemm_tn_bf16<0><<<dim3(128, 48), 256, 0, stream>>>(xp, wih_bf, b_ih, igates, T_STEPS, G3REC, D_MLP);

  // wavefront scan
  gru_gate0<<<8192, 256, 0, stream>>>(states, igates, start, mode_p, t0s, nseg_p,
                                      hg0, state0, b_n, Hf32, finals);
  for (int i = 1; i < K_MAX; ++i) {
    int mt = (8192 / (i + 1) + 127) / 128;  // count_i <= 8192/(i+1)
    gru_iter<<<dim3(mt, 32), 256, 0, stream>>>(states, igates, w_perm, t0s, counts,
                                               b_n, Hf32, finals, i);
  }
  gru_cleanup<<<512, 256, 0, stream>>>(states, igates, w_perm, t0s, len_s, counts,
                                       b_n, Hf32, finals);

  // post MLP + heads
  gemm_tn_bf16<1><<<dim3(128, 16), 256, 0, stream>>>(states, W1_bf, b1, y1, T_STEPS, D_MLP, D_REC);
  gemm_tn_bf16<1><<<dim3(128, 16), 256, 0, stream>>>(y1, W2_bf, b2, y2, T_STEPS, D_MLP, D_MLP);
  heads_kernel<<<8192, 64, 0, stream>>>(y2, Wv, bv, Wa, ba, Ws, bs, qout);
}

// Round 7
// 596.591 us; speedup vs baseline: 14.2270x; 1.0847x over previous
//
#include <hip/hip_runtime.h>
#include <hip/hip_bf16.h>
#include <cstdint>
#include <cstddef>

#define T_STEPS 8192
#define D_OBS 256
#define D_ACT 16
#define D_MLP 1024
#define D_REC 1024
#define G3REC 3072
#define K_MAX 20          // wavefront iterations 0..K_MAX-1; cleanup handles len > K_MAX
#define HCAP 4608         // Hf32 row capacity (nseg ~ 4096 +/- 45; 11-sigma headroom)

typedef short bf16x8_t __attribute__((ext_vector_type(8)));
typedef float f32x4_t __attribute__((ext_vector_type(4)));

__device__ __forceinline__ float b2f(unsigned short u) {
  union { uint32_t i; float f; } v; v.i = ((uint32_t)u) << 16; return v.f;
}
__device__ __forceinline__ unsigned short f2b(float f) {
  union { float f; uint32_t i; } v; v.f = f;
  uint32_t r = v.i + 0x7fffu + ((v.i >> 16) & 1u);
  return (unsigned short)(r >> 16);
}
__device__ __forceinline__ float mishf(float v) {
  float sp = (v > 15.f) ? v : log1pf(expf(v));
  return v * tanhf(sp);
}
__device__ __forceinline__ float sigmf(float x) { return 1.f / (1.f + expf(-x)); }

// async global->LDS, 16B per lane; LDS dest = wave-uniform base + lane*16.
__device__ __forceinline__ void gload_lds16(const void* g, void* l) {
  __builtin_amdgcn_global_load_lds((const __attribute__((address_space(1))) void*)g,
                                   (__attribute__((address_space(3))) void*)l, 16, 0, 0);
}

// LDS swizzle (bank-conflict fix, both-sides rule #21):
// [R][32]el bf16 tile as R*4 slots of 16B. slot s holds data chunk
// (row = s>>2, j = (s&3) ^ ((s>>3)&3)). Reads for (row,j) use
// slot row*4 + (j ^ ((row>>1)&3)). 16 rows/same-j -> 2 lanes/bank (free).
__device__ __forceinline__ int swz_src_j(int slot) {   // source chunk j for linear slot
  return (slot & 3) ^ ((slot >> 3) & 3);
}
__device__ __forceinline__ int swz_read_off(int row, int j) {  // element offset in tile
  return row * 32 + ((j ^ ((row >> 1) & 3)) << 3);
}

// ---- f32 -> bf16 conversion ----
__global__ __launch_bounds__(256) void cvt_f32_bf16(
    const float* __restrict__ in, unsigned short* __restrict__ out, int n4) {
  int stride = gridDim.x * blockDim.x;
  for (int j = blockIdx.x * blockDim.x + threadIdx.x; j < n4; j += stride) {
    float4 v = ((const float4*)in)[j];
    ushort4 o;
    o.x = f2b(v.x); o.y = f2b(v.y); o.z = f2b(v.z); o.w = f2b(v.w);
    ((ushort4*)out)[j] = o;
  }
}

// w_hh [3072,1024] f32 -> w_perm bf16 with row permutation: out row 3u+g = in row g*1024+u.
__global__ __launch_bounds__(256) void cvt_whh_perm(
    const float* __restrict__ in, unsigned short* __restrict__ out) {
  int r = blockIdx.x;                 // original row
  int g = r >> 10, u = r & 1023;
  unsigned short* dst = out + (size_t)(u * 3 + g) * D_REC;
  const float* src = in + (size_t)r * D_REC;
  for (int c = threadIdx.x * 4; c < D_REC; c += 1024) {
    float4 v = *(const float4*)&src[c];
    ushort4 o; o.x = f2b(v.x); o.y = f2b(v.y); o.z = f2b(v.z); o.w = f2b(v.w);
    *(ushort4*)&dst[c] = o;
  }
}

// C[M,N] = act(A[M,K] @ B[N,K]^T + bias[N]); A,B,C bf16, bias f32, f32 accum.
// Block tile (MT*32) x (NT*32), BK=32, 4 waves (2x2), each wave (MT*16)x(NT*16),
// dbuf global_load_lds staging + swizzled LDS (2-way max bank alias).
template <int ACT, int MT, int NT>
__global__ __launch_bounds__(256) void gemm_tn(
    const unsigned short* __restrict__ A,
    const unsigned short* __restrict__ B,
    const float* __restrict__ bias,
    unsigned short* __restrict__ C,
    int M, int N, int K) {
  constexpr int BM = MT * 32, BN = NT * 32;
  constexpr int CA = BM / 64, CB = BN / 64;   // staging chunks per thread
  __shared__ unsigned short lds_a[2][BM * 32];
  __shared__ unsigned short lds_b[2][BN * 32];
  const int tid = threadIdx.x;
  const int lane = tid & 63;
  const int wave = tid >> 6;
  const int wr = wave >> 1, wc = wave & 1;
  const int row0 = blockIdx.x * BM, col0 = blockIdx.y * BN;
  f32x4_t acc[MT][NT] = {};
  const int lrow = lane & 15, j = lane >> 4;
  // staging sources: chunk p -> slot = p*256 + tid, row = slot>>2, swizzled col
  const unsigned short* srcA[CA];
  const unsigned short* srcB[CB];
#pragma unroll
  for (int p = 0; p < CA; ++p) {
    int slot = p * 256 + tid;
    srcA[p] = &A[(size_t)(row0 + (slot >> 2)) * K + swz_src_j(slot) * 8];
  }
#pragma unroll
  for (int p = 0; p < CB; ++p) {
    int slot = p * 256 + tid;
    srcB[p] = &B[(size_t)(col0 + (slot >> 2)) * K + swz_src_j(slot) * 8];
  }
  const int so = wave * 512;  // per-wave lane-linear LDS base (elements)
  auto stage = [&](int buf, int k0) {
#pragma unroll
    for (int p = 0; p < CA; ++p)
      gload_lds16(srcA[p] + k0, &lds_a[buf][p * 2048 + so]);
#pragma unroll
    for (int p = 0; p < CB; ++p)
      gload_lds16(srcB[p] + k0, &lds_b[buf][p * 2048 + so]);
  };
  // precompute swizzled read offsets (K-invariant)
  int aoff[MT], boff[NT];
#pragma unroll
  for (int m = 0; m < MT; ++m)
    aoff[m] = swz_read_off(wr * (MT * 16) + m * 16 + lrow, j);
#pragma unroll
  for (int n = 0; n < NT; ++n)
    boff[n] = swz_read_off(wc * (NT * 16) + n * 16 + lrow, j);
  const int nk = K >> 5;
  stage(0, 0);
  __syncthreads();
  int cur = 0;
  for (int t = 0; t < nk; ++t) {
    if (t + 1 < nk) stage(cur ^ 1, (t + 1) << 5);
    bf16x8_t af[MT], bfr[NT];
#pragma unroll
    for (int m = 0; m < MT; ++m)
      af[m] = *(const bf16x8_t*)&lds_a[cur][aoff[m]];
#pragma unroll
    for (int n = 0; n < NT; ++n)
      bfr[n] = *(const bf16x8_t*)&lds_b[cur][boff[n]];
#pragma unroll
    for (int m = 0; m < MT; ++m)
#pragma unroll
      for (int n = 0; n < NT; ++n)
        acc[m][n] = __builtin_amdgcn_mfma_f32_16x16x32_bf16(af[m], bfr[n], acc[m][n], 0, 0, 0);
    __syncthreads();   // drains vmcnt(0): next buf staged; lgkm: cur reads done
    cur ^= 1;
  }
  // C/D layout (verified m89/m91): col = lane&15, row = (lane>>4)*4 + jj
#pragma unroll
  for (int n = 0; n < NT; ++n) {
    int col = col0 + wc * (NT * 16) + n * 16 + lrow;
    float bv = bias[col];
#pragma unroll
    for (int m = 0; m < MT; ++m) {
#pragma unroll
      for (int jj = 0; jj < 4; ++jj) {
        int row = row0 + wr * (MT * 16) + m * 16 + j * 4 + jj;
        float v = acc[m][n][jj] + bv;
        if (ACT) v = mishf(v);
        C[(size_t)row * N + col] = f2b(v);
      }
    }
  }
}

// ---- start-flag dtype detection (int32 vs uint8) + nseg zeroing ----
__global__ void detect_start_mode(const unsigned int* __restrict__ w,
                                  int* __restrict__ mode, int* __restrict__ nseg) {
  if (threadIdx.x == 0 && blockIdx.x == 0) {
    int m = 0;
    for (int i = 0; i < 64; ++i)
      if (w[i] > 1u) m = 1;
    *mode = m;  // 1 = uint8, 0 = int32
    *nseg = 0;
  }
}
__device__ __forceinline__ int start_flag(const void* start, int mode, int t) {
  if (mode) return ((const unsigned char*)start)[t] != 0;
  return ((const int*)start)[t] != 0;
}

// ---- segment list: every t with (t==0 || start[t]) begins a segment ----
__global__ __launch_bounds__(256) void seg_build(
    const void* __restrict__ start, const int* __restrict__ mode_p,
    int* __restrict__ t0_raw, int* __restrict__ len_raw, int* __restrict__ nseg) {
  int t = blockIdx.x * blockDim.x + threadIdx.x;
  if (t >= T_STEPS) return;
  int mode = *mode_p;
  if (t != 0 && !start_flag(start, mode, t)) return;
  int len = 1;
  while (t + len < T_STEPS && !start_flag(start, mode, t + len)) ++len;
  int slot = atomicAdd(nseg, 1);
  t0_raw[slot] = t;
  len_raw[slot] = len;
}

// ---- counting sort by length (descending); counts[i] = #segments with len > i ----
__global__ __launch_bounds__(256) void seg_sort(
    const int* __restrict__ t0_raw, const int* __restrict__ len_raw,
    const int* __restrict__ nseg_p,
    int* __restrict__ t0s, int* __restrict__ len_s, int* __restrict__ counts) {
  __shared__ int hist[K_MAX + 2], off[K_MAX + 2];
  int tid = threadIdx.x;
  int n = *nseg_p;
  if (tid < K_MAX + 2) hist[tid] = 0;
  __syncthreads();
  for (int s = tid; s < n; s += 256)
    atomicAdd(&hist[min(len_raw[s], K_MAX + 1)], 1);
  __syncthreads();
  if (tid == 0) {
    int acc = 0;
    for (int b = K_MAX + 1; b >= 1; --b) { off[b] = acc; acc += hist[b]; }
    for (int i = 0; i <= K_MAX; ++i) {
      int c = 0;
      for (int b = i + 1; b <= K_MAX + 1; ++b) c += hist[b];
      counts[i] = c;
    }
  }
  __syncthreads();
  for (int s = tid; s < n; s += 256) {
    int pos = atomicAdd(&off[min(len_raw[s], K_MAX + 1)], 1);
    t0s[pos] = t0_raw[s];
    len_s[pos] = len_raw[s];
  }
}

// ---- hg0 = w_hh(f32) @ state0(f32): only segment containing t=0 needs a nonzero h ----
__global__ __launch_bounds__(256) void matvec0(
    const float* __restrict__ w_hh, const float* __restrict__ state0,
    float* __restrict__ hg0) {
  int g = threadIdx.x >> 4, l16 = threadIdx.x & 15;
  int row = blockIdx.x * 16 + g;
  const float* wr = w_hh + (size_t)row * D_REC;
  float s = 0.f;
#pragma unroll
  for (int i = 0; i < 16; ++i) {
    int c = (l16 + i * 16) * 4;
    float4 w4 = *(const float4*)&wr[c];
    float4 h4 = *(const float4*)&state0[c];
    s += w4.x * h4.x + w4.y * h4.y + w4.z * h4.z + w4.w * h4.w;
  }
#pragma unroll
  for (int o = 1; o < 16; o <<= 1) s += __shfl_xor(s, o);
  if (l16 == 0) hg0[row] = s;
}

// ---- iteration 0 gate: h_prev = state0 (seg at t=0, no reset) or 0 ----
__global__ __launch_bounds__(256) void gru_gate0(
    unsigned short* __restrict__ states, const unsigned short* __restrict__ igates,
    const void* __restrict__ start, const int* __restrict__ mode_p,
    const int* __restrict__ t0s, const int* __restrict__ nseg_p,
    const float* __restrict__ hg0, const float* __restrict__ state0,
    const float* __restrict__ b_n, float* __restrict__ Hf32,
    float* __restrict__ finals) {
  int p = blockIdx.x;
  if (p >= *nseg_p) return;
  int t0 = t0s[p];
  int mode = *mode_p;
  bool use_s0 = (t0 == 0) && !start_flag(start, mode, 0);
  size_t ib = (size_t)t0 * G3REC;
  for (int u = threadIdx.x; u < D_REC; u += 256) {
    float hp = use_s0 ? state0[u] : 0.f;
    float hr = use_s0 ? hg0[u] : 0.f;
    float hz = use_s0 ? hg0[D_REC + u] : 0.f;
    float hn = use_s0 ? hg0[2 * D_REC + u] : 0.f;
    float r = sigmf(b2f(igates[ib + u]) + hr);
    float z = sigmf(b2f(igates[ib + D_REC + u]) + hz);
    float n = tanhf(b2f(igates[ib + 2 * D_REC + u]) + r * (hn + b_n[u]));
    float hnew = n + z * (hp - n);
    if (p < HCAP) Hf32[(size_t)p * D_REC + u] = hnew;
    states[(size_t)t0 * D_REC + u] = f2b(hnew);
    if (t0 == T_STEPS - 1) finals[u] = hnew;
  }
}

// ---- fused wavefront iteration i>=1: hg GEMM (A gathered from states) + gate epilogue.
// Tile: 128 segments x 96 w_perm-rows (=32 units x 3 gates). 4 waves of 32x96.
// Double-buffered + swizzled staging.
__global__ __launch_bounds__(256) void gru_iter(
    unsigned short* __restrict__ states,
    const unsigned short* __restrict__ igates,
    const unsigned short* __restrict__ w_perm,
    const int* __restrict__ t0s, const int* __restrict__ counts,
    const float* __restrict__ b_n, float* __restrict__ Hf32,
    float* __restrict__ finals, int iter) {
  const int count = counts[iter];
  const int row0 = blockIdx.x * 128;
  if (row0 >= count) return;
  const int u0 = blockIdx.y * 32;
  const int col0 = u0 * 3;
  __shared__ __align__(16) float smem_f[128 * 98];        // 50176 B
  unsigned short* sb = (unsigned short*)smem_f;
  // a bufs: [0,4096),[4096,8192); b bufs: [8192,11264),[11264,14336) (elements)
  float* hgl = smem_f;                                    // [128][98] f32 (after K-loop)
  const int tid = threadIdx.x;
  const int lane = tid & 63, wave = tid >> 6;
  const int rA = tid >> 2;
  const int c8sw = swz_src_j(tid) * 8;     // swizzled source chunk (same for p=0,1)
  int gA0 = (row0 + rA < count) ? (t0s[row0 + rA] + iter - 1) : (t0s[0] + iter - 1);
  int gA1 = (row0 + rA + 64 < count) ? (t0s[row0 + rA + 64] + iter - 1) : (t0s[0] + iter - 1);
  const unsigned short* srcA0 = states + (size_t)gA0 * D_REC + c8sw;
  const unsigned short* srcA1 = states + (size_t)gA1 * D_REC + c8sw;
  const unsigned short* srcB0 = w_perm + (size_t)(col0 + rA) * D_REC + c8sw;
  const unsigned short* srcB1 = w_perm + (size_t)(col0 + 64 + rA) * D_REC + c8sw; // waves 0,1
  const int so = wave * 512;
  auto stage = [&](int buf, int k0) {
    unsigned short* la = sb + buf * 4096 + so;
    unsigned short* lb = sb + 8192 + buf * 3072 + so;
    gload_lds16(srcA0 + k0, la);
    gload_lds16(srcA1 + k0, la + 2048);
    gload_lds16(srcB0 + k0, lb);
    if (wave < 2)
      gload_lds16(srcB1 + k0, lb + 2048);
  };
  f32x4_t acc[2][6] = {};
  const int lrow = lane & 15, j = lane >> 4;
  int aoff[2], boff[6];
#pragma unroll
  for (int m = 0; m < 2; ++m)
    aoff[m] = swz_read_off(wave * 32 + m * 16 + lrow, j);
#pragma unroll
  for (int n = 0; n < 6; ++n)
    boff[n] = swz_read_off(n * 16 + lrow, j);
  stage(0, 0);
  __syncthreads();
  int cur = 0;
  for (int t = 0; t < 32; ++t) {
    if (t + 1 < 32) stage(cur ^ 1, (t + 1) << 5);
    const unsigned short* ca = sb + cur * 4096;
    const unsigned short* cb = sb + 8192 + cur * 3072;
    bf16x8_t af[2], bfr[6];
#pragma unroll
    for (int m = 0; m < 2; ++m)
      af[m] = *(const bf16x8_t*)&ca[aoff[m]];
#pragma unroll
    for (int n = 0; n < 6; ++n)
      bfr[n] = *(const bf16x8_t*)&cb[boff[n]];
#pragma unroll
    for (int m = 0; m < 2; ++m)
#pragma unroll
      for (int n = 0; n < 6; ++n)
        acc[m][n] = __builtin_amdgcn_mfma_f32_16x16x32_bf16(af[m], bfr[n], acc[m][n], 0, 0, 0);
    __syncthreads();
    cur ^= 1;
  }
  // dump acc tile to LDS (row-local x 96 cols, stride 98 to dodge bank conflicts)
#pragma unroll
  for (int m = 0; m < 2; ++m)
#pragma unroll
    for (int n = 0; n < 6; ++n)
#pragma unroll
      for (int jj = 0; jj < 4; ++jj) {
        int row = wave * 32 + m * 16 + j * 4 + jj;
        hgl[row * 98 + n * 16 + lrow] = acc[m][n][jj];
      }
  __syncthreads();
  // gate epilogue: 128 segs x 32 units
  for (int idx = tid; idx < 128 * 32; idx += 256) {
    int pl = idx >> 5, ul = idx & 31;
    int p = row0 + pl;
    if (p >= count) continue;
    int t = t0s[p] + iter;
    int u = u0 + ul;
    float hr = hgl[pl * 98 + 3 * ul + 0];
    float hz = hgl[pl * 98 + 3 * ul + 1];
    float hn = hgl[pl * 98 + 3 * ul + 2];
    size_t ib = (size_t)t * G3REC;
    float hp = Hf32[(size_t)p * D_REC + u];
    float r = sigmf(b2f(igates[ib + u]) + hr);
    float z = sigmf(b2f(igates[ib + D_REC + u]) + hz);
    float n = tanhf(b2f(igates[ib + 2 * D_REC + u]) + r * (hn + b_n[u]));
    float hnew = n + z * (hp - n);
    Hf32[(size_t)p * D_REC + u] = hnew;
    states[(size_t)t * D_REC + u] = f2b(hnew);
    if (t == T_STEPS - 1) finals[u] = hnew;
  }
}

// ---- sequential tail for segments with len > K_MAX (w.h.p. none) ----
__global__ __launch_bounds__(256) void gru_cleanup(
    unsigned short* __restrict__ states, const unsigned short* __restrict__ igates,
    const unsigned short* __restrict__ w_perm,
    const int* __restrict__ t0s, const int* __restrict__ len_s,
    const int* __restrict__ counts, const float* __restrict__ b_n,
    const float* __restrict__ Hf32, float* __restrict__ finals) {
  int p = blockIdx.x;
  if (p >= counts[K_MAX]) return;  // segments with len > K_MAX (sorted first)
  int t0 = t0s[p], len = len_s[p];
  __shared__ float h[D_REC];
  __shared__ float hgl[G3REC];
  const int tid = threadIdx.x;
  for (int u = tid; u < D_REC; u += 256) h[u] = Hf32[(size_t)p * D_REC + u];
  __syncthreads();
  const int g = tid >> 4, l16 = tid & 15;
  for (int s = K_MAX; s < len; ++s) {
    int t = t0 + s;
    float hreg[64];
#pragma unroll
    for (int i = 0; i < 8; ++i) {
      float4 a = *(const float4*)&h[l16 * 8 + i * 128];
      float4 b = *(const float4*)&h[l16 * 8 + i * 128 + 4];
      hreg[i * 8 + 0] = a.x; hreg[i * 8 + 1] = a.y; hreg[i * 8 + 2] = a.z; hreg[i * 8 + 3] = a.w;
      hreg[i * 8 + 4] = b.x; hreg[i * 8 + 5] = b.y; hreg[i * 8 + 6] = b.z; hreg[i * 8 + 7] = b.w;
    }
    for (int row = g; row < G3REC; row += 16) {
      const unsigned short* wrow = w_perm + (size_t)row * D_REC;
      float sum = 0.f;
#pragma unroll
      for (int i = 0; i < 8; ++i) {
        bf16x8_t wv = *(const bf16x8_t*)&wrow[l16 * 8 + i * 128];
#pragma unroll
        for (int jj = 0; jj < 8; ++jj)
          sum += b2f((unsigned short)wv[jj]) * hreg[i * 8 + jj];
      }
#pragma unroll
      for (int o = 1; o < 16; o <<= 1) sum += __shfl_xor(sum, o);
      if (l16 == 0) hgl[row] = sum;
    }
    __syncthreads();
    size_t ib = (size_t)t * G3REC;
    for (int u = tid; u < D_REC; u += 256) {
      float r = sigmf(b2f(igates[ib + u]) + hgl[3 * u + 0]);
      float z = sigmf(b2f(igates[ib + D_REC + u]) + hgl[3 * u + 1]);
      float n = tanhf(b2f(igates[ib + 2 * D_REC + u]) + r * (hgl[3 * u + 2] + b_n[u]));
      float hnew = n + z * (h[u] - n);
      h[u] = hnew;
      states[(size_t)t * D_REC + u] = f2b(hnew);
      if (t == T_STEPS - 1) finals[u] = hnew;
    }
    __syncthreads();
  }
}

// ---- heads + dueling epilogue (one wave per timestep) ----
__global__ __launch_bounds__(64) void heads_kernel(
    const unsigned short* __restrict__ y,
    const float* __restrict__ Wv, const float* __restrict__ bv,
    const float* __restrict__ Wa, const float* __restrict__ ba,
    const float* __restrict__ Ws, const float* __restrict__ bs,
    float* __restrict__ q) {
  const int t = blockIdx.x, lane = threadIdx.x;
  const unsigned short* yr = y + (size_t)t * D_MLP;
  float yv[16];
#pragma unroll
  for (int c = 0; c < 2; ++c) {
    bf16x8_t v = *(const bf16x8_t*)&yr[lane * 16 + c * 8];
#pragma unroll
    for (int j = 0; j < 8; ++j) yv[c * 8 + j] = b2f((unsigned short)v[j]);
  }
  float mine = 0.f;
  for (int o = 0; o < 18; ++o) {
    const float* w = (o < 16) ? (Wa + (size_t)o * D_MLP) : (o == 16 ? Wv : Ws);
    float s = 0.f;
#pragma unroll
    for (int c = 0; c < 4; ++c) {
      float4 wv = *(const float4*)&w[lane * 16 + c * 4];
      s += wv.x * yv[c * 4 + 0] + wv.y * yv[c * 4 + 1] +
           wv.z * yv[c * 4 + 2] + wv.w * yv[c * 4 + 3];
    }
#pragma unroll
    for (int off = 1; off < 64; off <<= 1) s += __shfl_xor(s, off);
    if (lane == o) mine = s;
  }
  if (lane < 16) mine += ba[lane];
  else if (lane == 16) mine += bv[0];
  else if (lane == 17) mine += bs[0];
  float a = (lane < 16) ? mine : 0.f;
  float ss = a * a;
#pragma unroll
  for (int off = 1; off < 64; off <<= 1) ss += __shfl_xor(ss, off);
  float an = a / (1e-6f + sqrtf(ss));
  float ms = (lane < 16) ? an : 0.f;
#pragma unroll
  for (int off = 1; off < 64; off <<= 1) ms += __shfl_xor(ms, off);
  float adv = an - ms * (1.f / 16.f);
  float val = __shfl(mine, 16);
  float sc = __shfl(mine, 17);
  if (lane < 16) q[(size_t)t * D_ACT + lane] = val + sc * adv;
}

extern "C" void kernel_launch(void* const* d_in, const int* in_sizes, int n_in,
                              void* d_out, int out_size, void* d_ws, size_t ws_size,
                              hipStream_t stream) {
  const float* x      = (const float*)d_in[0];
  const float* state0 = (const float*)d_in[1];
  const void*  start  = d_in[2];
  const float* W_pre  = (const float*)d_in[3];
  const float* b_pre  = (const float*)d_in[4];
  const float* w_ih   = (const float*)d_in[5];
  const float* w_hh   = (const float*)d_in[6];
  const float* b_ih   = (const float*)d_in[7];
  const float* b_n    = (const float*)d_in[8];
  const float* W1     = (const float*)d_in[9];
  const float* b1     = (const float*)d_in[10];
  const float* W2     = (const float*)d_in[11];
  const float* b2     = (const float*)d_in[12];
  const float* Wv     = (const float*)d_in[13];
  const float* bv     = (const float*)d_in[14];
  const float* Wa     = (const float*)d_in[15];
  const float* ba     = (const float*)d_in[16];
  const float* Ws     = (const float*)d_in[17];
  const float* bs     = (const float*)d_in[18];

  // workspace layout (phases: A=pre/igates, B=scan, C=post). Peak < 99 MB.
  char* ws = (char*)d_ws;
  const size_t MB = 1ull << 20;
  unsigned short* igates = (unsigned short*)(ws);
  unsigned short* y2     = igates;
  unsigned short* xp     = (unsigned short*)(ws + 48 * MB);
  float*          Hf32   = (float*)(ws + 48 * MB);
  unsigned short* y1     = xp;
  unsigned short* states = (unsigned short*)(ws + 66 * MB);
  unsigned short* x_bf   = (unsigned short*)(ws + 82 * MB);
  unsigned short* w_perm = (unsigned short*)(ws + 82 * MB);
  unsigned short* Wpre_bf= (unsigned short*)(ws + 88 * MB);
  unsigned short* wih_bf = (unsigned short*)(ws + 88 * MB + 512 * 1024);
  unsigned short* W1_bf  = (unsigned short*)(ws + 94 * MB + 512 * 1024);
  unsigned short* W2_bf  = (unsigned short*)(ws + 96 * MB + 512 * 1024);
  char* seg = ws + 98 * MB + 512 * 1024;
  int* t0_raw  = (int*)(seg);
  int* len_raw = (int*)(seg + 32768);
  int* t0s     = (int*)(seg + 65536);
  int* len_s   = (int*)(seg + 98304);
  int* counts  = (int*)(seg + 131072);
  int* nseg_p  = (int*)(seg + 131072 + 128);
  int* mode_p  = (int*)(seg + 131072 + 192);
  float* hg0   = (float*)(seg + 131072 + 256);
  float* qout   = (float*)d_out;
  float* finals = qout + (size_t)T_STEPS * D_ACT;

  detect_start_mode<<<1, 64, 0, stream>>>((const unsigned int*)start, mode_p, nseg_p);
  cvt_f32_bf16<<<512, 256, 0, stream>>>(x,     x_bf,    (T_STEPS * D_OBS) / 4);
  cvt_f32_bf16<<<256, 256, 0, stream>>>(W_pre, Wpre_bf, (D_MLP * D_OBS) / 4);
  cvt_f32_bf16<<<768, 256, 0, stream>>>(w_ih,  wih_bf,  (G3REC * D_MLP) / 4);
  cvt_f32_bf16<<<512, 256, 0, stream>>>(W1,    W1_bf,   (D_MLP * D_REC) / 4);
  cvt_f32_bf16<<<512, 256, 0, stream>>>(W2,    W2_bf,   (D_MLP * D_MLP) / 4);
  seg_build<<<32, 256, 0, stream>>>(start, mode_p, t0_raw, len_raw, nseg_p);
  seg_sort<<<1, 256, 0, stream>>>(t0_raw, len_raw, nseg_p, t0s, len_s, counts);
  matvec0<<<192, 256, 0, stream>>>(w_hh, state0, hg0);

  // pre-MLP (64^2 tile), then w_hh permute-convert, then igates GEMM (128^2 tile)
  gemm_tn<1, 2, 2><<<dim3(128, 16), 256, 0, stream>>>(x_bf, Wpre_bf, b_pre, xp, T_STEPS, D_MLP, D_OBS);
  cvt_whh_perm<<<3072, 256, 0, stream>>>(w_hh, w_perm);
  gemm_tn<0, 4, 4><<<dim3(64, 24), 256, 0, stream>>>(xp, wih_bf, b_ih, igates, T_STEPS, G3REC, D_MLP);

  // wavefront scan
  gru_gate0<<<8192, 256, 0, stream>>>(states, igates, start, mode_p, t0s, nseg_p,
                                      hg0, state0, b_n, Hf32, finals);
  for (int i = 1; i < K_MAX; ++i) {
    int mt = (8192 / (i + 1) + 127) / 128;  // count_i <= 8192/(i+1)
    gru_iter<<<dim3(mt, 32), 256, 0, stream>>>(states, igates, w_perm, t0s, counts,
                                               b_n, Hf32, finals, i);
  }
  gru_cleanup<<<512, 256, 0, stream>>>(states, igates, w_perm, t0s, len_s, counts,
                                       b_n, Hf32, finals);

  // post MLP (64^2 tiles) + heads
  gemm_tn<1, 2, 2><<<dim3(128, 16), 256, 0, stream>>>(states, W1_bf, b1, y1, T_STEPS, D_MLP, D_REC);
  gemm_tn<1, 2, 2><<<dim3(128, 16), 256, 0, stream>>>(y1, W2_bf, b2, y2, T_STEPS, D_MLP, D_MLP);
  heads_kernel<<<8192, 64, 0, stream>>>(y2, Wv, bv, Wa, ba, Ws, bs, qout);
}